// Round 3
// baseline (38224.246 us; speedup 1.0000x reference)
//
#include <hip/hip_runtime.h>
#include <math.h>

#define B     512
#define SEQL  128
#define PT    5
#define EH    256
#define ZS    128
#define DH    512
#define NM    20
#define NMAXT 256

__device__ __forceinline__ float sigf(float x) { return 1.0f / (1.0f + expf(-x)); }

// bank swizzle key for ks in [0,4): spreads (n,ks) lanes 2-way over 32 banks
__device__ __forceinline__ int swzkey(int ks) { return ((ks & 1) << 2) ^ ((ks >> 1) * 24); }

__device__ __forceinline__ void ctr_wait(int* c, int target) {
    if (threadIdx.x == 0) {
        while (__hip_atomic_load(c, __ATOMIC_ACQUIRE, __HIP_MEMORY_SCOPE_AGENT) < target)
            __builtin_amdgcn_s_sleep(2);
    }
    __syncthreads();
}
__device__ __forceinline__ void ctr_bump(int* c) {
    __syncthreads();
    if (threadIdx.x == 0) {
        __threadfence();
        __hip_atomic_fetch_add(c, 1, __ATOMIC_RELEASE, __HIP_MEMORY_SCOPE_AGENT);
    }
}

#define FMA16(w, q0, q1, q2, q3)                                              \
    acc[0]=fmaf(w,q0.x,acc[0]);  acc[1]=fmaf(w,q0.y,acc[1]);                  \
    acc[2]=fmaf(w,q0.z,acc[2]);  acc[3]=fmaf(w,q0.w,acc[3]);                  \
    acc[4]=fmaf(w,q1.x,acc[4]);  acc[5]=fmaf(w,q1.y,acc[5]);                  \
    acc[6]=fmaf(w,q1.z,acc[6]);  acc[7]=fmaf(w,q1.w,acc[7]);                  \
    acc[8]=fmaf(w,q2.x,acc[8]);  acc[9]=fmaf(w,q2.y,acc[9]);                  \
    acc[10]=fmaf(w,q2.z,acc[10]); acc[11]=fmaf(w,q2.w,acc[11]);               \
    acc[12]=fmaf(w,q3.x,acc[12]); acc[13]=fmaf(w,q3.y,acc[13]);               \
    acc[14]=fmaf(w,q3.z,acc[14]); acc[15]=fmaf(w,q3.w,acc[15]);

#define XSUM(v) v += __shfl_xor(v,1); v += __shfl_xor(v,2); v += __shfl_xor(v,4); \
                v += __shfl_xor(v,8); v += __shfl_xor(v,16); v += __shfl_xor(v,32);

// ---------- generic transpose with zero-pad ----------
__global__ void transpose_pad(const float* __restrict__ in, float* __restrict__ out,
                              int rows, int cols, int rpad)
{
    int idx = blockIdx.x * 256 + threadIdx.x;
    if (idx >= cols * rpad) return;
    int c = idx / rpad, r = idx - c * rpad;
    out[idx] = (r < rows) ? in[(size_t)r * cols + c] : 0.0f;
}

// =================== persistent encoder ===================
// grid 256 = 8 bg x (2 dir x 16 ng); block 1024 = 16 waves (g4 x bh4); lane = (n16, ks4)
__global__ __launch_bounds__(1024) void enc_persist(
    const float* __restrict__ s,
    const float* __restrict__ WihF, const float* __restrict__ WhhF, const float* __restrict__ bF,
    const float* __restrict__ WihB, const float* __restrict__ WhhB, const float* __restrict__ bB,
    float* __restrict__ hf0, float* __restrict__ hf1,
    float* __restrict__ hb0, float* __restrict__ hb1,
    int* __restrict__ ce)
{
    __shared__ float W_s[16384];     // [256 k][64 rows] swizzled
    __shared__ float gate_s[4096];   // [4 g][16 n][64 b] swizzled
    __shared__ float c_s[1024];      // [16 n][64 b]

    const int tid = threadIdx.x;
    const int bg  = blockIdx.x >> 5;
    const int r5  = blockIdx.x & 31;
    const int dir = r5 >> 4;
    const int ng  = r5 & 15;
    const int n0  = ng * 16;

    const float* Whh  = dir ? WhhB : WhhF;
    const float* Wih  = dir ? WihB : WihF;
    const float* bias = dir ? bB : bF;
    float* buf0 = dir ? hb0 : hf0;
    float* buf1 = dir ? hb1 : hf1;

    // ---- load Whh slice into LDS (once) ----
    {
        const int r = tid & 63;
        const int g = r >> 4, n = r & 15;
        const size_t grow = (size_t)(g * EH + n0 + n);
        const int kq0 = tid >> 6;
        #pragma unroll
        for (int i = 0; i < 4; ++i) {
            const int k = (kq0 + i * 16) * 4;
            const float4 w = *(const float4*)&Whh[grow * EH + k];
            const int rs = r ^ swzkey(k >> 6);
            W_s[(k + 0) * 64 + rs] = w.x;
            W_s[(k + 1) * 64 + rs] = w.y;
            W_s[(k + 2) * 64 + rs] = w.z;
            W_s[(k + 3) * 64 + rs] = w.w;
        }
    }
    c_s[tid & 1023] = 0.0f;

    // pointwise identity
    const int pb = tid & 63;
    const int pn = tid >> 6;            // 0..15
    const int bglob = bg * 64 + pb;
    float wih5[4][5], bb4[4];
    #pragma unroll
    for (int g2 = 0; g2 < 4; ++g2) {
        bb4[g2] = bias[g2 * EH + n0 + pn];
        #pragma unroll
        for (int j = 0; j < 5; ++j)
            wih5[g2][j] = Wih[(size_t)(g2 * EH + n0 + pn) * PT + j];
    }

    // G-phase identity
    const int lane = tid & 63;
    const int wv   = tid >> 6;
    const int gw   = wv & 3;
    const int bh   = wv >> 2;
    const int nl   = lane & 15;
    const int ks   = lane >> 4;
    const int rsw  = (gw * 16 + nl) ^ swzkey(ks);
    const int bb0  = bg * 64 + bh * 16;
    const int kb   = ks * 64;

    __syncthreads();

    float* hin = buf0;
    float* hout = buf1;

    #pragma unroll 1
    for (int t = 0; t < SEQL; ++t) {
        if (t > 0) ctr_wait(&ce[(t - 1) * 16 + dir * 8 + bg], 16);

        float acc[16];
        #pragma unroll
        for (int j = 0; j < 16; ++j) acc[j] = 0.0f;
        {
            const float* hp = hin + (size_t)kb * B + bb0;
            const float* wp = &W_s[kb * 64 + rsw];
            #pragma unroll 4
            for (int kk = 0; kk < 64; ++kk) {
                const float w = wp[kk * 64];
                const float4 q0 = *(const float4*)(hp + (size_t)kk * B + 0);
                const float4 q1 = *(const float4*)(hp + (size_t)kk * B + 4);
                const float4 q2 = *(const float4*)(hp + (size_t)kk * B + 8);
                const float4 q3 = *(const float4*)(hp + (size_t)kk * B + 12);
                FMA16(w, q0, q1, q2, q3)
            }
        }
        #pragma unroll
        for (int j = 0; j < 16; ++j) {
            float v = acc[j];
            v += __shfl_xor(v, 16);
            v += __shfl_xor(v, 32);
            acc[j] = v;
        }
        if (ks == 0) {
            #pragma unroll
            for (int q = 0; q < 4; ++q) {
                const int boff = bh * 16 + ((q * 4) ^ ((nl & 3) << 2));
                float4 v = make_float4(acc[q*4+0], acc[q*4+1], acc[q*4+2], acc[q*4+3]);
                *(float4*)&gate_s[(gw * 16 + nl) * 64 + boff] = v;
            }
        }
        __syncthreads();

        // pointwise
        const int ts = dir ? (SEQL - 1 - t) : t;
        const float* xp = &s[((size_t)ts * B + bglob) * PT];
        const float x0 = xp[0], x1 = xp[1], x2 = xp[2], x3 = xp[3], x4 = xp[4];
        const int r2 = pb & 15;
        float gv[4];
        #pragma unroll
        for (int g2 = 0; g2 < 4; ++g2) {
            const int addr = (g2 * 16 + pn) * 64 + (pb & 48)
                           + ((r2 & 12) ^ ((pn & 3) << 2)) + (r2 & 3);
            float v = gate_s[addr] + bb4[g2];
            v = fmaf(wih5[g2][0], x0, v); v = fmaf(wih5[g2][1], x1, v);
            v = fmaf(wih5[g2][2], x2, v); v = fmaf(wih5[g2][3], x3, v);
            v = fmaf(wih5[g2][4], x4, v);
            gv[g2] = v;
        }
        const float cold = c_s[pn * 64 + pb];
        const float cv = sigf(gv[1]) * cold + sigf(gv[0]) * tanhf(gv[2]);
        c_s[pn * 64 + pb] = cv;
        hout[(size_t)(n0 + pn) * B + bglob] = sigf(gv[3]) * tanhf(cv);

        ctr_bump(&ce[t * 16 + dir * 8 + bg]);
        float* tmp = hout; hout = hin; hin = tmp;
    }
}

// =================== latent chain (small, per-step-free) ===================
__global__ __launch_bounds__(256) void latent2(
    const float* __restrict__ hfT, const float* __restrict__ hbT,
    const float* __restrict__ Wmu, const float* __restrict__ bmu,
    const float* __restrict__ Wsig, const float* __restrict__ bsig,
    const float* __restrict__ zepsT, float* __restrict__ zT)
{
    const int lane = threadIdx.x & 63;
    const int wv   = __builtin_amdgcn_readfirstlane(threadIdx.x >> 6);
    const int b    = blockIdx.x * 64 + lane;
    const int n0   = blockIdx.y * 8 + wv * 2;

    float am[2] = {}, as2[2] = {};
    #pragma unroll 4
    for (int k0 = 0; k0 < 2 * EH; k0 += 4) {
        const float* hsrc = (k0 < EH) ? hfT : hbT;
        const int kk = k0 & (EH - 1);
        const float a0 = hsrc[(size_t)(kk + 0) * B + b];
        const float a1 = hsrc[(size_t)(kk + 1) * B + b];
        const float a2 = hsrc[(size_t)(kk + 2) * B + b];
        const float a3 = hsrc[(size_t)(kk + 3) * B + b];
        #pragma unroll
        for (int j = 0; j < 2; ++j) {
            const float4 wm = *(const float4*)&Wmu[((size_t)(n0 + j)) * (2 * EH) + k0];
            const float4 ws = *(const float4*)&Wsig[((size_t)(n0 + j)) * (2 * EH) + k0];
            float u = am[j], v = as2[j];
            u = fmaf(a0, wm.x, u); u = fmaf(a1, wm.y, u); u = fmaf(a2, wm.z, u); u = fmaf(a3, wm.w, u);
            v = fmaf(a0, ws.x, v); v = fmaf(a1, ws.y, v); v = fmaf(a2, ws.z, v); v = fmaf(a3, ws.w, v);
            am[j] = u; as2[j] = v;
        }
    }
    #pragma unroll
    for (int j = 0; j < 2; ++j) {
        const int n = n0 + j;
        const float mu = am[j] + bmu[n];
        const float sg = expf(0.5f * (as2[j] + bsig[n]));
        zT[(size_t)n * B + b] = fmaf(sg, zepsT[(size_t)n * B + b], mu);
    }
}

__global__ __launch_bounds__(256) void h02(
    const float* __restrict__ zT, const float* __restrict__ Wh0,
    const float* __restrict__ bh0, float* __restrict__ hT)
{
    const int lane = threadIdx.x & 63;
    const int wv   = __builtin_amdgcn_readfirstlane(threadIdx.x >> 6);
    const int b    = blockIdx.x * 64 + lane;
    const int n0   = blockIdx.y * 32 + wv * 8;

    float acc[8] = {};
    #pragma unroll 2
    for (int k0 = 0; k0 < ZS; k0 += 4) {
        const float a0 = zT[(size_t)(k0 + 0) * B + b];
        const float a1 = zT[(size_t)(k0 + 1) * B + b];
        const float a2 = zT[(size_t)(k0 + 2) * B + b];
        const float a3 = zT[(size_t)(k0 + 3) * B + b];
        #pragma unroll
        for (int r = 0; r < 8; ++r) {
            const float4 w = *(const float4*)&Wh0[((size_t)(n0 + r)) * ZS + k0];
            float v = acc[r];
            v = fmaf(a0, w.x, v); v = fmaf(a1, w.y, v);
            v = fmaf(a2, w.z, v); v = fmaf(a3, w.w, v);
            acc[r] = v;
        }
    }
    #pragma unroll
    for (int r = 0; r < 8; ++r)
        hT[(size_t)(n0 + r) * B + b] = tanhf(acc[r] + bh0[n0 + r]);
}

__global__ __launch_bounds__(256) void cz2(
    const float* __restrict__ zT, const float* __restrict__ Wih,
    const float* __restrict__ bias, float* __restrict__ CzT)
{
    const int lane = threadIdx.x & 63;
    const int wv   = __builtin_amdgcn_readfirstlane(threadIdx.x >> 6);
    const int b    = blockIdx.x * 64 + lane;
    const int r0   = blockIdx.y * 32 + wv * 8;

    float acc[8] = {};
    #pragma unroll 4
    for (int k = 0; k < ZS; ++k) {
        const float a = zT[(size_t)k * B + b];
        #pragma unroll
        for (int r = 0; r < 8; ++r)
            acc[r] = fmaf(a, Wih[(size_t)(r0 + r) * 133 + 5 + k], acc[r]);
    }
    #pragma unroll
    for (int r = 0; r < 8; ++r)
        CzT[(size_t)(r0 + r) * B + b] = acc[r] + bias[r0 + r];
}

// =================== persistent decoder ===================
// grid 256 = 8 bg x 32 ng; block 1024; waves (g4 x bh4); lane = (n16, ks4)
__global__ __launch_bounds__(1024) void dec_persist(
    const float* __restrict__ Whh,   // [2048][512]
    const float* __restrict__ Wih,   // [2048][133]
    const float* __restrict__ CzT,   // [2048][512]  (includes dec bias)
    const float* __restrict__ Wdec,  // [123][512]
    const float* __restrict__ bdec,
    const float* __restrict__ geps,  // [256][512][20][2]
    const float* __restrict__ penu,  // [256][512][3]
    float* __restrict__ hA, float* __restrict__ hB,   // [512][512], hA holds h0
    float* __restrict__ out,         // [256][512][5]
    int* __restrict__ ch, int* __restrict__ c2)
{
    __shared__ float W_s[32768];
    __shared__ float gate_s[4096];
    __shared__ float c_s[1024];
    __shared__ float y_s[256];

    const int tid = threadIdx.x;
    const int bg  = blockIdx.x >> 5;
    const int ng  = blockIdx.x & 31;
    const int n0  = ng * 16;

    {
        const int r = tid & 63;
        const int g = r >> 4, n = r & 15;
        const size_t grow = (size_t)(g * DH + n0 + n);
        const int kq0 = tid >> 6;
        #pragma unroll
        for (int i = 0; i < 8; ++i) {
            const int k = (kq0 + i * 16) * 4;
            const float4 w = *(const float4*)&Whh[grow * DH + k];
            const int rs = r ^ swzkey(k >> 7);
            W_s[(k + 0) * 64 + rs] = w.x;
            W_s[(k + 1) * 64 + rs] = w.y;
            W_s[(k + 2) * 64 + rs] = w.z;
            W_s[(k + 3) * 64 + rs] = w.w;
        }
    }
    c_s[tid & 1023] = 0.0f;

    const int pb = tid & 63;
    const int pn = tid >> 6;
    const int bglob = bg * 64 + pb;
    float wp5[4][5];
    #pragma unroll
    for (int g2 = 0; g2 < 4; ++g2)
        #pragma unroll
        for (int j = 0; j < 5; ++j)
            wp5[g2][j] = Wih[(size_t)(g2 * DH + n0 + pn) * 133 + j];

    const int lane = tid & 63;
    const int wv   = tid >> 6;
    const int gw   = wv & 3;
    const int bh   = wv >> 2;
    const int nl   = lane & 15;
    const int ks   = lane >> 4;
    const int rsw  = (gw * 16 + nl) ^ swzkey(ks);
    const int bb0  = bg * 64 + bh * 16;
    const int kb   = ks * 128;

    __syncthreads();

    float* hin = hA;
    float* hout = hB;

    #pragma unroll 1
    for (int t = 0; t < NMAXT; ++t) {
        // ---- G phase: gate partial sums over own k-slice ----
        float acc[16];
        #pragma unroll
        for (int j = 0; j < 16; ++j) acc[j] = 0.0f;
        {
            const float* hp = hin + (size_t)kb * B + bb0;
            const float* wp = &W_s[kb * 64 + rsw];
            #pragma unroll 4
            for (int kk = 0; kk < 128; ++kk) {
                const float w = wp[kk * 64];
                const float4 q0 = *(const float4*)(hp + (size_t)kk * B + 0);
                const float4 q1 = *(const float4*)(hp + (size_t)kk * B + 4);
                const float4 q2 = *(const float4*)(hp + (size_t)kk * B + 8);
                const float4 q3 = *(const float4*)(hp + (size_t)kk * B + 12);
                FMA16(w, q0, q1, q2, q3)
            }
        }
        #pragma unroll
        for (int j = 0; j < 16; ++j) {
            float v = acc[j];
            v += __shfl_xor(v, 16);
            v += __shfl_xor(v, 32);
            acc[j] = v;
        }
        if (ks == 0) {
            #pragma unroll
            for (int q = 0; q < 4; ++q) {
                const int boff = bh * 16 + ((q * 4) ^ ((nl & 3) << 2));
                float4 v = make_float4(acc[q*4+0], acc[q*4+1], acc[q*4+2], acc[q*4+3]);
                *(float4*)&gate_s[(gw * 16 + nl) * 64 + boff] = v;
            }
        }
        // wait for prev points of step t-1 (overlaps nothing at t=0)
        if (t > 0) {
            if (tid == 0)
                while (__hip_atomic_load(&c2[(t - 1) * 8 + bg], __ATOMIC_ACQUIRE, __HIP_MEMORY_SCOPE_AGENT) < 32)
                    __builtin_amdgcn_s_sleep(2);
        }
        __syncthreads();

        // ---- pointwise LSTM update ----
        float p0, p1, p2, p3, p4;
        if (t == 0) { p0 = 0.f; p1 = 0.f; p2 = 1.f; p3 = 0.f; p4 = 0.f; }
        else {
            const float* pp = &out[((size_t)(t - 1) * B + bglob) * 5];
            p0 = pp[0]; p1 = pp[1]; p2 = pp[2]; p3 = pp[3]; p4 = pp[4];
        }
        const int r2 = pb & 15;
        float gv[4];
        #pragma unroll
        for (int g2 = 0; g2 < 4; ++g2) {
            const int addr = (g2 * 16 + pn) * 64 + (pb & 48)
                           + ((r2 & 12) ^ ((pn & 3) << 2)) + (r2 & 3);
            float v = gate_s[addr] + CzT[(size_t)(g2 * DH + n0 + pn) * B + bglob];
            v = fmaf(wp5[g2][0], p0, v); v = fmaf(wp5[g2][1], p1, v);
            v = fmaf(wp5[g2][2], p2, v); v = fmaf(wp5[g2][3], p3, v);
            v = fmaf(wp5[g2][4], p4, v);
            gv[g2] = v;
        }
        const float cold = c_s[pn * 64 + pb];
        const float cv = sigf(gv[1]) * cold + sigf(gv[0]) * tanhf(gv[2]);
        c_s[pn * 64 + pb] = cv;
        hout[(size_t)(n0 + pn) * B + bglob] = sigf(gv[3]) * tanhf(cv);

        // publish h', then wait all 32 ng-blocks of this bg
        ctr_bump(&ch[t * 8 + bg]);
        ctr_wait(&ch[t * 8 + bg], 32);

        // ---- Y phase: y = h' @ Wdec^T + bdec for this block's 2 batches ----
        {
            const int bp = wv & 1;
            const int cseg = wv >> 1;
            const int by = bg * 64 + ng * 2 + bp;
            float hv8[8];
            #pragma unroll
            for (int i = 0; i < 8; ++i)
                hv8[i] = hout[(size_t)(i * 64 + lane) * B + by];
            #pragma unroll
            for (int ci = 0; ci < 16; ++ci) {
                const int c = cseg * 16 + ci;
                float sv = 0.0f;
                if (c < 123) {
                    const float* wr = &Wdec[(size_t)c * DH];
                    #pragma unroll
                    for (int i = 0; i < 8; ++i)
                        sv = fmaf(wr[i * 64 + lane], hv8[i], sv);
                }
                XSUM(sv)
                if (lane == 0 && c < 123) y_s[bp * 128 + c] = sv + bdec[c];
            }
        }
        __syncthreads();

        // ---- sampler: waves 0,1 (one per batch) ----
        if (wv < 2) {
            const int bp = wv;
            const int by = bg * 64 + ng * 2 + bp;
            const float* y = &y_s[bp * 128];
            const int m = lane;
            float pv = (m < NM) ? y[6 * m] : -1e30f;
            float mm = pv;
            mm = fmaxf(mm, __shfl_xor(mm, 1));  mm = fmaxf(mm, __shfl_xor(mm, 2));
            mm = fmaxf(mm, __shfl_xor(mm, 4));  mm = fmaxf(mm, __shfl_xor(mm, 8));
            mm = fmaxf(mm, __shfl_xor(mm, 16)); mm = fmaxf(mm, __shfl_xor(mm, 32));
            float pe = 0.f, tx = 0.f, ty = 0.f;
            if (m < NM) {
                pe = expf(pv - mm);
                const float mx = y[6 * m + 1], my = y[6 * m + 2];
                const float sx = expf(y[6 * m + 3]), sy = expf(y[6 * m + 4]);
                const float cor = tanhf(y[6 * m + 5]);
                const float l21 = cor / sx;
                const float l22 = sqrtf(fmaxf(sy * sy - l21 * l21, 1e-6f));
                const float* ep = &geps[(((size_t)t * B) + by) * (NM * 2) + 2 * m];
                const float e1 = ep[0], e2 = ep[1];
                tx = pe * fmaf(sx, e1, mx);
                ty = pe * (my + fmaf(l21, e1, l22 * e2));
            }
            XSUM(pe) XSUM(tx) XSUM(ty)
            if (lane == 0) {
                const float q0 = y[120], q1 = y[121], q2 = y[122];
                const float qm = fmaxf(q0, fmaxf(q1, q2));
                const float e0 = expf(q0 - qm), e1q = expf(q1 - qm), e2q = expf(q2 - qm);
                const float qs = e0 + e1q + e2q;
                const float* u = &penu[(((size_t)t * B) + by) * 3];
                float* o = &out[(((size_t)t * B) + by) * 5];
                o[0] = tx / pe;
                o[1] = ty / pe;
                o[2] = (u[0] < e0  / qs) ? 1.f : 0.f;
                o[3] = (u[1] < e1q / qs) ? 1.f : 0.f;
                o[4] = (u[2] < e2q / qs) ? 1.f : 0.f;
            }
        }
        ctr_bump(&c2[t * 8 + bg]);

        float* tmp = hout; hout = hin; hin = tmp;
    }
}

extern "C" void kernel_launch(void* const* d_in, const int* in_sizes, int n_in,
                              void* d_out, int out_size, void* d_ws, size_t ws_size,
                              hipStream_t stream)
{
    (void)in_sizes; (void)n_in; (void)out_size; (void)ws_size;

    const float* s      = (const float*)d_in[0];
    const float* WihF   = (const float*)d_in[1];
    const float* WhhF   = (const float*)d_in[2];
    const float* bF     = (const float*)d_in[3];
    const float* WihB   = (const float*)d_in[4];
    const float* WhhB   = (const float*)d_in[5];
    const float* bB     = (const float*)d_in[6];
    const float* Wmu    = (const float*)d_in[7];
    const float* bmu    = (const float*)d_in[8];
    const float* Wsig   = (const float*)d_in[9];
    const float* bsig   = (const float*)d_in[10];
    const float* Wh0    = (const float*)d_in[11];
    const float* bh0    = (const float*)d_in[12];
    const float* decWih = (const float*)d_in[13];
    const float* decWhh = (const float*)d_in[14];
    const float* decB   = (const float*)d_in[15];
    const float* Wdec   = (const float*)d_in[16];
    const float* bdec   = (const float*)d_in[17];
    const float* zeps   = (const float*)d_in[18];
    const float* geps   = (const float*)d_in[19];
    const float* penu   = (const float*)d_in[20];

    float* out = (float*)d_out;
    float* p   = (float*)d_ws;

    float* hf0 = p; p += 131072;       // zeroed
    float* hb0 = p; p += 131072;       // zeroed
    int*   ce  = (int*)p; p += 2048;   // zeroed
    int*   ch  = (int*)p; p += 2048;   // zeroed
    int*   c2  = (int*)p; p += 2048;   // zeroed
    float* hf1 = p; p += 131072;
    float* hb1 = p; p += 131072;
    float* hTA = p; p += 262144;
    float* hTB = p; p += 262144;
    float* zT  = p; p += 65536;
    float* CzT = p; p += 1048576;
    float* zepsT = p; p += 65536;

    // zero: hf0, hb0, ce, ch, c2 (contiguous)
    hipMemsetAsync((void*)hf0, 0, (size_t)(131072 + 131072 + 6144) * sizeof(float), stream);

    transpose_pad<<<dim3(256), 256, 0, stream>>>(zeps, zepsT, B, ZS, B);

    enc_persist<<<dim3(256), 1024, 0, stream>>>(
        s, WihF, WhhF, bF, WihB, WhhB, bB, hf0, hf1, hb0, hb1, ce);

    // final encoder hidden states land in the "0" buffers (t=127 writes buf0)
    latent2<<<dim3(8, 16), 256, 0, stream>>>(hf0, hb0, Wmu, bmu, Wsig, bsig, zepsT, zT);
    h02<<<dim3(8, 16), 256, 0, stream>>>(zT, Wh0, bh0, hTA);
    cz2<<<dim3(8, 64), 256, 0, stream>>>(zT, decWih, decB, CzT);

    dec_persist<<<dim3(256), 1024, 0, stream>>>(
        decWhh, decWih, CzT, Wdec, bdec, geps, penu, hTA, hTB, out, ch, c2);
}

// Round 4
// 17932.782 us; speedup vs baseline: 2.1315x; 2.1315x over previous
//
#include <hip/hip_runtime.h>
#include <math.h>

#define B     512
#define SEQL  128
#define PT    5
#define EH    256
#define ZS    128
#define DH    512
#define NM    20
#define NMAXT 256

__device__ __forceinline__ float sigf(float x) { return 1.0f / (1.0f + expf(-x)); }

#define FMA8(m, av, lo, hi)                                                   \
    acc[m][0]=fmaf(av,lo.x,acc[m][0]); acc[m][1]=fmaf(av,lo.y,acc[m][1]);     \
    acc[m][2]=fmaf(av,lo.z,acc[m][2]); acc[m][3]=fmaf(av,lo.w,acc[m][3]);     \
    acc[m][4]=fmaf(av,hi.x,acc[m][4]); acc[m][5]=fmaf(av,hi.y,acc[m][5]);     \
    acc[m][6]=fmaf(av,hi.z,acc[m][6]); acc[m][7]=fmaf(av,hi.w,acc[m][7]);

// ---------- generic transpose with zero-pad: out[c*rpad + r] ----------
__global__ void transpose_pad(const float* __restrict__ in, float* __restrict__ out,
                              int rows, int cols, int rpad)
{
    int idx = blockIdx.x * 256 + threadIdx.x;
    if (idx >= cols * rpad) return;
    int c = idx / rpad, r = idx - c * rpad;
    out[idx] = (r < rows) ? in[(size_t)r * cols + c] : 0.0f;
}

// =======================================================================
// Encoder step. grid 512: x = dir*256 + bg*32 + ng. block 256 = 4 waves.
// Block tile: 32 gate-rows (4g x 8n, n0=ng*8) x 64 b. Waves k-split K=256 (64 each).
// W in LDS (swizzled), h-operand direct from global (L1/L2-hot).
// =======================================================================
__global__ __launch_bounds__(256) void enc_step3(
    const float* __restrict__ s,
    const float* __restrict__ WihF, const float* __restrict__ WhhF, const float* __restrict__ bF,
    const float* __restrict__ WihB, const float* __restrict__ WhhB, const float* __restrict__ bB,
    const float* __restrict__ hfin, float* __restrict__ hfout, float* __restrict__ cf,
    const float* __restrict__ hbin, float* __restrict__ hbout, float* __restrict__ cb,
    int t)
{
    __shared__ float lds[8704];   // max(W stage 8192, partials 4*32*68=8704)

    const int tid = threadIdx.x;
    const int x   = blockIdx.x;
    const int ng  = x & 31;
    const int bg  = (x >> 5) & 7;
    const int dir = x >> 8;
    const int n0  = ng * 8;
    const int b0  = bg * 64;

    const float* Whh  = dir ? WhhB : WhhF;
    const float* Wih  = dir ? WihB : WihF;
    const float* bias = dir ? bB   : bF;
    const float* hin  = dir ? hbin : hfin;
    float* hout       = dir ? hbout: hfout;
    float* c          = dir ? cb   : cf;
    const int ts = dir ? (SEQL - 1 - t) : t;

    // ---- stage W: 4 waves x 32 rows x 16 f4-slots, XOR-swizzled by row>>2 ----
    #pragma unroll
    for (int i = 0; i < 8; ++i) {
        const int fidx = i * 256 + tid;            // 0..2047 f4
        const int w  = fidx >> 9;
        const int rem = fidx & 511;
        const int r  = rem >> 4, s5 = rem & 15;
        const int g  = r >> 3, nn = r & 7;
        const float4 wv = *(const float4*)&Whh[(size_t)(g * EH + n0 + nn) * EH + w * 64 + s5 * 4];
        *(float4*)&lds[((w * 32 + r) * 16 + (s5 ^ ((r >> 2) & 7))) * 4] = wv;
    }
    __syncthreads();

    // ---- G phase: wave wv handles k in [wv*64, wv*64+64) ----
    const int lane = tid & 63;
    const int wv   = tid >> 6;
    const int ri   = lane & 7;      // row-group: rows ri*4..ri*4+3
    const int bi   = lane >> 3;     // col-group: cols bi*8..bi*8+7
    const float* hcol = hin + b0 + bi * 8;

    float acc[4][8];
    #pragma unroll
    for (int m = 0; m < 4; ++m)
        #pragma unroll
        for (int j = 0; j < 8; ++j) acc[m][j] = 0.0f;

    #pragma unroll 4
    for (int j4 = 0; j4 < 16; ++j4) {
        float4 a[4];
        #pragma unroll
        for (int m = 0; m < 4; ++m)
            a[m] = *(const float4*)&lds[((wv * 32 + ri * 4 + m) * 16 + (j4 ^ ri)) * 4];
        float4 blo[4], bhi[4];
        #pragma unroll
        for (int jj = 0; jj < 4; ++jj) {
            const float* hp = hcol + (size_t)(wv * 64 + j4 * 4 + jj) * B;
            blo[jj] = *(const float4*)hp;
            bhi[jj] = *(const float4*)(hp + 4);
        }
        #pragma unroll
        for (int m = 0; m < 4; ++m) {
            FMA8(m, a[m].x, blo[0], bhi[0])
            FMA8(m, a[m].y, blo[1], bhi[1])
            FMA8(m, a[m].z, blo[2], bhi[2])
            FMA8(m, a[m].w, blo[3], bhi[3])
        }
    }
    __syncthreads();   // done reading W_s; reuse as partial buffer

    // ---- write k-partials: part[wv][32 rows][68 pad] ----
    #pragma unroll
    for (int m = 0; m < 4; ++m) {
        float* pr = &lds[(wv * 32 + ri * 4 + m) * 68 + bi * 8];
        *(float4*)pr       = make_float4(acc[m][0], acc[m][1], acc[m][2], acc[m][3]);
        *(float4*)(pr + 4) = make_float4(acc[m][4], acc[m][5], acc[m][6], acc[m][7]);
    }
    __syncthreads();

    // ---- reduce + fused LSTM pointwise: 8n x 64b cells, 2 b per thread ----
    const int nn = tid & 7;
    const int c0 = (tid >> 3) * 2;
    const int bgl = b0 + c0;

    float ps[4][2];
    #pragma unroll
    for (int g = 0; g < 4; ++g) {
        const int r = g * 8 + nn;
        ps[g][0] = lds[r * 68 + c0]     + lds[(32 + r) * 68 + c0]
                 + lds[(64 + r) * 68 + c0] + lds[(96 + r) * 68 + c0];
        ps[g][1] = lds[r * 68 + c0 + 1] + lds[(32 + r) * 68 + c0 + 1]
                 + lds[(64 + r) * 68 + c0 + 1] + lds[(96 + r) * 68 + c0 + 1];
    }

    #pragma unroll
    for (int bb2 = 0; bb2 < 2; ++bb2) {
        const int b = bgl + bb2;
        const float* xp = &s[((size_t)ts * B + b) * PT];
        const float x0 = xp[0], x1 = xp[1], x2 = xp[2], x3 = xp[3], x4 = xp[4];
        float gv[4];
        #pragma unroll
        for (int g = 0; g < 4; ++g) {
            const int grow = g * EH + n0 + nn;
            const float* wr = Wih + (size_t)grow * PT;
            float v = ps[g][bb2] + bias[grow];
            v = fmaf(x0, wr[0], v); v = fmaf(x1, wr[1], v); v = fmaf(x2, wr[2], v);
            v = fmaf(x3, wr[3], v); v = fmaf(x4, wr[4], v);
            gv[g] = v;
        }
        const size_t idx = (size_t)(n0 + nn) * B + b;
        const float cv = sigf(gv[1]) * c[idx] + sigf(gv[0]) * tanhf(gv[2]);
        c[idx] = cv;
        hout[idx] = sigf(gv[3]) * tanhf(cv);
    }
}

// =======================================================================
// Decoder step. grid 512: ng = x&63, bg = x>>6 (XCD-local W/CzT slices).
// Block tile: 32 gate-rows (4g x 8n, n0=ng*8) x 64 b. Waves k-split K=512 (128 each, 2 chunks).
// =======================================================================
__global__ __launch_bounds__(256) void dec_step3(
    const float* __restrict__ hin, float* __restrict__ hout, float* __restrict__ cT,
    const float* __restrict__ CzT, const float* __restrict__ Whh,
    const float* __restrict__ Wih, const float* __restrict__ prevPt, int t)
{
    __shared__ float lds[16384];  // W stage 16384 floats (64KB) >= partials 8704

    const int tid = threadIdx.x;
    const int x   = blockIdx.x;
    const int ng  = x & 63;
    const int bg  = x >> 6;
    const int n0  = ng * 8;
    const int b0  = bg * 64;

    // ---- stage W: 4 waves x 32 rows x 32 f4-slots (2 chunks of 16), swizzled ----
    #pragma unroll
    for (int i = 0; i < 16; ++i) {
        const int fidx = i * 256 + tid;            // 0..4095 f4
        const int w   = fidx >> 10;
        const int rem = fidx & 1023;
        const int r   = rem >> 5, s5 = rem & 31;
        const int g   = r >> 3, nn = r & 7;
        const int sl  = (s5 & 16) | ((s5 & 15) ^ ((r >> 2) & 7));
        const float4 wv = *(const float4*)&Whh[(size_t)(g * DH + n0 + nn) * DH + w * 128 + s5 * 4];
        *(float4*)&lds[((w * 32 + r) * 32 + sl) * 4] = wv;
    }
    __syncthreads();

    const int lane = tid & 63;
    const int wv   = tid >> 6;
    const int ri   = lane & 7;
    const int bi   = lane >> 3;
    const float* hcol = hin + b0 + bi * 8;

    float acc[4][8];
    #pragma unroll
    for (int m = 0; m < 4; ++m)
        #pragma unroll
        for (int j = 0; j < 8; ++j) acc[m][j] = 0.0f;

    #pragma unroll
    for (int cc = 0; cc < 2; ++cc) {
        const int kb = wv * 128 + cc * 64;
        #pragma unroll 4
        for (int j4 = 0; j4 < 16; ++j4) {
            float4 a[4];
            #pragma unroll
            for (int m = 0; m < 4; ++m)
                a[m] = *(const float4*)&lds[((wv * 32 + ri * 4 + m) * 32 + cc * 16 + (j4 ^ ri)) * 4];
            float4 blo[4], bhi[4];
            #pragma unroll
            for (int jj = 0; jj < 4; ++jj) {
                const float* hp = hcol + (size_t)(kb + j4 * 4 + jj) * B;
                blo[jj] = *(const float4*)hp;
                bhi[jj] = *(const float4*)(hp + 4);
            }
            #pragma unroll
            for (int m = 0; m < 4; ++m) {
                FMA8(m, a[m].x, blo[0], bhi[0])
                FMA8(m, a[m].y, blo[1], bhi[1])
                FMA8(m, a[m].z, blo[2], bhi[2])
                FMA8(m, a[m].w, blo[3], bhi[3])
            }
        }
    }
    __syncthreads();

    #pragma unroll
    for (int m = 0; m < 4; ++m) {
        float* pr = &lds[(wv * 32 + ri * 4 + m) * 68 + bi * 8];
        *(float4*)pr       = make_float4(acc[m][0], acc[m][1], acc[m][2], acc[m][3]);
        *(float4*)(pr + 4) = make_float4(acc[m][4], acc[m][5], acc[m][6], acc[m][7]);
    }
    __syncthreads();

    // ---- reduce + pointwise ----
    const int nn = tid & 7;
    const int c0 = (tid >> 3) * 2;
    const int bgl = b0 + c0;

    float ps[4][2];
    #pragma unroll
    for (int g = 0; g < 4; ++g) {
        const int r = g * 8 + nn;
        ps[g][0] = lds[r * 68 + c0]     + lds[(32 + r) * 68 + c0]
                 + lds[(64 + r) * 68 + c0] + lds[(96 + r) * 68 + c0];
        ps[g][1] = lds[r * 68 + c0 + 1] + lds[(32 + r) * 68 + c0 + 1]
                 + lds[(64 + r) * 68 + c0 + 1] + lds[(96 + r) * 68 + c0 + 1];
    }

    #pragma unroll
    for (int bb2 = 0; bb2 < 2; ++bb2) {
        const int b = bgl + bb2;
        float p0, p1, p2, p3, p4;
        if (t == 0) { p0 = 0.f; p1 = 0.f; p2 = 1.f; p3 = 0.f; p4 = 0.f; }
        else {
            const float* pp = &prevPt[(size_t)b * 5];
            p0 = pp[0]; p1 = pp[1]; p2 = pp[2]; p3 = pp[3]; p4 = pp[4];
        }
        float gv[4];
        #pragma unroll
        for (int g = 0; g < 4; ++g) {
            const int grow = g * DH + n0 + nn;
            const float* wr = Wih + (size_t)grow * 133;
            float v = ps[g][bb2] + CzT[(size_t)grow * B + b];
            v = fmaf(p0, wr[0], v); v = fmaf(p1, wr[1], v); v = fmaf(p2, wr[2], v);
            v = fmaf(p3, wr[3], v); v = fmaf(p4, wr[4], v);
            gv[g] = v;
        }
        const size_t idx = (size_t)(n0 + nn) * B + b;
        const float cv = sigf(gv[1]) * cT[idx] + sigf(gv[0]) * tanhf(gv[2]);
        cT[idx] = cv;
        hout[idx] = sigf(gv[3]) * tanhf(cv);
    }
}

// =======================================================================
// Y = h @ Wdec^T + bdec fused with GMM sampler. grid 128 x 128 thr, 4 batches/block.
// =======================================================================
__global__ __launch_bounds__(128) void ysamp3(
    const float* __restrict__ hT, const float* __restrict__ WdecT,  // [512][128] zero-padded
    const float* __restrict__ bdec,
    const float* __restrict__ geps, const float* __restrict__ penu,
    float* __restrict__ out, int t)
{
    const int col = threadIdx.x;
    const int b0  = blockIdx.x * 4;

    float acc[4] = {};
    #pragma unroll 8
    for (int k = 0; k < DH; ++k) {
        const float w   = WdecT[(size_t)k * 128 + col];
        const float4 hq = *(const float4*)&hT[(size_t)k * B + b0];
        acc[0] = fmaf(w, hq.x, acc[0]); acc[1] = fmaf(w, hq.y, acc[1]);
        acc[2] = fmaf(w, hq.z, acc[2]); acc[3] = fmaf(w, hq.w, acc[3]);
    }

    __shared__ float Y[4][128];
    const float bd = (col < 123) ? bdec[col] : 0.0f;
    #pragma unroll
    for (int j = 0; j < 4; ++j) Y[j][col] = acc[j] + bd;
    __syncthreads();

    if (threadIdx.x < 4) {
        const int b = b0 + threadIdx.x;
        const float* y = Y[threadIdx.x];

        float mmax = y[0];
        #pragma unroll
        for (int m = 1; m < NM; ++m) mmax = fmaxf(mmax, y[6 * m]);
        float pe[NM];
        float psum = 0.f;
        #pragma unroll
        for (int m = 0; m < NM; ++m) { pe[m] = expf(y[6 * m] - mmax); psum += pe[m]; }

        const float* ep = geps + ((size_t)t * B + b) * NM * 2;
        float dx = 0.f, dy = 0.f;
        #pragma unroll
        for (int m = 0; m < NM; ++m) {
            const float pim = pe[m] / psum;
            const float mx = y[6 * m + 1], my = y[6 * m + 2];
            const float sx = expf(y[6 * m + 3]), sy = expf(y[6 * m + 4]);
            const float cor = tanhf(y[6 * m + 5]);
            const float l21 = cor / sx;
            const float l22 = sqrtf(fmaxf(sy * sy - l21 * l21, 1e-6f));
            const float e1 = ep[2 * m], e2 = ep[2 * m + 1];
            dx += pim * (mx + sx * e1);
            dy += pim * (my + fmaf(l21, e1, l22 * e2));
        }

        const float q0 = y[120], q1 = y[121], q2 = y[122];
        const float qm = fmaxf(q0, fmaxf(q1, q2));
        const float e0 = expf(q0 - qm), e1q = expf(q1 - qm), e2q = expf(q2 - qm);
        const float qs = e0 + e1q + e2q;

        const float* u = penu + ((size_t)t * B + b) * 3;
        float* o = out + ((size_t)t * B + b) * 5;
        o[0] = dx;
        o[1] = dy;
        o[2] = (u[0] < e0  / qs) ? 1.f : 0.f;
        o[3] = (u[1] < e1q / qs) ? 1.f : 0.f;
        o[4] = (u[2] < e2q / qs) ? 1.f : 0.f;
    }
}

// ---------------- latent chain (R1-proven) ----------------
__global__ __launch_bounds__(256) void latent2(
    const float* __restrict__ hfT, const float* __restrict__ hbT,
    const float* __restrict__ Wmu, const float* __restrict__ bmu,
    const float* __restrict__ Wsig, const float* __restrict__ bsig,
    const float* __restrict__ zepsT, float* __restrict__ zT)
{
    const int lane = threadIdx.x & 63;
    const int wv   = __builtin_amdgcn_readfirstlane(threadIdx.x >> 6);
    const int b    = blockIdx.x * 64 + lane;
    const int n0   = blockIdx.y * 8 + wv * 2;

    float am[2] = {}, as2[2] = {};
    #pragma unroll 4
    for (int k0 = 0; k0 < 2 * EH; k0 += 4) {
        const float* hsrc = (k0 < EH) ? hfT : hbT;
        const int kk = k0 & (EH - 1);
        const float a0 = hsrc[(size_t)(kk + 0) * B + b];
        const float a1 = hsrc[(size_t)(kk + 1) * B + b];
        const float a2 = hsrc[(size_t)(kk + 2) * B + b];
        const float a3 = hsrc[(size_t)(kk + 3) * B + b];
        #pragma unroll
        for (int j = 0; j < 2; ++j) {
            const float4 wm = *(const float4*)&Wmu[((size_t)(n0 + j)) * (2 * EH) + k0];
            const float4 ws = *(const float4*)&Wsig[((size_t)(n0 + j)) * (2 * EH) + k0];
            float u = am[j], v = as2[j];
            u = fmaf(a0, wm.x, u); u = fmaf(a1, wm.y, u); u = fmaf(a2, wm.z, u); u = fmaf(a3, wm.w, u);
            v = fmaf(a0, ws.x, v); v = fmaf(a1, ws.y, v); v = fmaf(a2, ws.z, v); v = fmaf(a3, ws.w, v);
            am[j] = u; as2[j] = v;
        }
    }
    #pragma unroll
    for (int j = 0; j < 2; ++j) {
        const int n = n0 + j;
        const float mu = am[j] + bmu[n];
        const float sg = expf(0.5f * (as2[j] + bsig[n]));
        zT[(size_t)n * B + b] = fmaf(sg, zepsT[(size_t)n * B + b], mu);
    }
}

__global__ __launch_bounds__(256) void h02(
    const float* __restrict__ zT, const float* __restrict__ Wh0,
    const float* __restrict__ bh0, float* __restrict__ hT)
{
    const int lane = threadIdx.x & 63;
    const int wv   = __builtin_amdgcn_readfirstlane(threadIdx.x >> 6);
    const int b    = blockIdx.x * 64 + lane;
    const int n0   = blockIdx.y * 32 + wv * 8;

    float acc[8] = {};
    #pragma unroll 2
    for (int k0 = 0; k0 < ZS; k0 += 4) {
        const float a0 = zT[(size_t)(k0 + 0) * B + b];
        const float a1 = zT[(size_t)(k0 + 1) * B + b];
        const float a2 = zT[(size_t)(k0 + 2) * B + b];
        const float a3 = zT[(size_t)(k0 + 3) * B + b];
        #pragma unroll
        for (int r = 0; r < 8; ++r) {
            const float4 w = *(const float4*)&Wh0[((size_t)(n0 + r)) * ZS + k0];
            float v = acc[r];
            v = fmaf(a0, w.x, v); v = fmaf(a1, w.y, v);
            v = fmaf(a2, w.z, v); v = fmaf(a3, w.w, v);
            acc[r] = v;
        }
    }
    #pragma unroll
    for (int r = 0; r < 8; ++r)
        hT[(size_t)(n0 + r) * B + b] = tanhf(acc[r] + bh0[n0 + r]);
}

__global__ __launch_bounds__(256) void cz2(
    const float* __restrict__ zT, const float* __restrict__ Wih,
    const float* __restrict__ bias, float* __restrict__ CzT)
{
    const int lane = threadIdx.x & 63;
    const int wv   = __builtin_amdgcn_readfirstlane(threadIdx.x >> 6);
    const int b    = blockIdx.x * 64 + lane;
    const int r0   = blockIdx.y * 32 + wv * 8;

    float acc[8] = {};
    #pragma unroll 4
    for (int k = 0; k < ZS; ++k) {
        const float a = zT[(size_t)k * B + b];
        #pragma unroll
        for (int r = 0; r < 8; ++r)
            acc[r] = fmaf(a, Wih[(size_t)(r0 + r) * 133 + 5 + k], acc[r]);
    }
    #pragma unroll
    for (int r = 0; r < 8; ++r)
        CzT[(size_t)(r0 + r) * B + b] = acc[r] + bias[r0 + r];
}

extern "C" void kernel_launch(void* const* d_in, const int* in_sizes, int n_in,
                              void* d_out, int out_size, void* d_ws, size_t ws_size,
                              hipStream_t stream)
{
    (void)in_sizes; (void)n_in; (void)out_size; (void)ws_size;

    const float* s      = (const float*)d_in[0];
    const float* WihF   = (const float*)d_in[1];
    const float* WhhF   = (const float*)d_in[2];
    const float* bF     = (const float*)d_in[3];
    const float* WihB   = (const float*)d_in[4];
    const float* WhhB   = (const float*)d_in[5];
    const float* bB     = (const float*)d_in[6];
    const float* Wmu    = (const float*)d_in[7];
    const float* bmu    = (const float*)d_in[8];
    const float* Wsig   = (const float*)d_in[9];
    const float* bsig   = (const float*)d_in[10];
    const float* Wh0    = (const float*)d_in[11];
    const float* bh0    = (const float*)d_in[12];
    const float* decWih = (const float*)d_in[13];
    const float* decWhh = (const float*)d_in[14];
    const float* decB   = (const float*)d_in[15];
    const float* Wdec   = (const float*)d_in[16];
    const float* bdec   = (const float*)d_in[17];
    const float* zeps   = (const float*)d_in[18];
    const float* geps   = (const float*)d_in[19];
    const float* penu   = (const float*)d_in[20];

    float* out = (float*)d_out;
    float* p   = (float*)d_ws;

    float* hf0  = p; p += 131072;   // zeroed
    float* hb0  = p; p += 131072;   // zeroed
    float* cf   = p; p += 131072;   // zeroed
    float* cb   = p; p += 131072;   // zeroed
    float* cdT  = p; p += 262144;   // zeroed
    float* hf1  = p; p += 131072;
    float* hb1  = p; p += 131072;
    float* hA   = p; p += 262144;
    float* hB   = p; p += 262144;
    float* zT   = p; p += 65536;
    float* CzT  = p; p += 1048576;
    float* zepsT= p; p += 65536;
    float* WdecT= p; p += 65536;

    hipMemsetAsync((void*)hf0, 0, (size_t)(4 * 131072 + 262144) * sizeof(float), stream);

    transpose_pad<<<dim3(256), 256, 0, stream>>>(zeps, zepsT, B, ZS, B);
    transpose_pad<<<dim3(256), 256, 0, stream>>>(Wdec, WdecT, 123, DH, 128);

    for (int t = 0; t < SEQL; ++t) {
        const float* hfin = (t & 1) ? hf1 : hf0;  float* hfout = (t & 1) ? hf0 : hf1;
        const float* hbin = (t & 1) ? hb1 : hb0;  float* hbout = (t & 1) ? hb0 : hb1;
        enc_step3<<<dim3(512), 256, 0, stream>>>(
            s, WihF, WhhF, bF, WihB, WhhB, bB,
            hfin, hfout, cf, hbin, hbout, cb, t);
    }
    // t=127 (odd) wrote hf0/hb0
    latent2<<<dim3(8, 16), 256, 0, stream>>>(hf0, hb0, Wmu, bmu, Wsig, bsig, zepsT, zT);
    h02<<<dim3(8, 16), 256, 0, stream>>>(zT, Wh0, bh0, hA);
    cz2<<<dim3(8, 64), 256, 0, stream>>>(zT, decWih, decB, CzT);

    for (int t = 0; t < NMAXT; ++t) {
        const float* hin = (t & 1) ? hB : hA;
        float* hout      = (t & 1) ? hA : hB;
        dec_step3<<<dim3(512), 256, 0, stream>>>(
            hin, hout, cdT, CzT, decWhh, decWih,
            t ? (out + (size_t)(t - 1) * B * 5) : out, t);
        ysamp3<<<dim3(128), 128, 0, stream>>>(hout, WdecT, bdec, geps, penu, out, t);
    }
}

// Round 5
// 12230.828 us; speedup vs baseline: 3.1252x; 1.4662x over previous
//
#include <hip/hip_runtime.h>
#include <math.h>

#define B     512
#define SEQL  128
#define PT    5
#define EH    256
#define ZS    128
#define DH    512
#define NM    20
#define NMAXT 256

__device__ __forceinline__ float sigf(float x) { return 1.0f / (1.0f + expf(-x)); }

#define FMA8(m, av, lo, hi)                                                   \
    acc[m][0]=fmaf(av,lo.x,acc[m][0]); acc[m][1]=fmaf(av,lo.y,acc[m][1]);     \
    acc[m][2]=fmaf(av,lo.z,acc[m][2]); acc[m][3]=fmaf(av,lo.w,acc[m][3]);     \
    acc[m][4]=fmaf(av,hi.x,acc[m][4]); acc[m][5]=fmaf(av,hi.y,acc[m][5]);     \
    acc[m][6]=fmaf(av,hi.z,acc[m][6]); acc[m][7]=fmaf(av,hi.w,acc[m][7]);

#define XSUM(v) v += __shfl_xor(v,1); v += __shfl_xor(v,2); v += __shfl_xor(v,4); \
                v += __shfl_xor(v,8); v += __shfl_xor(v,16); v += __shfl_xor(v,32);

// ---------- generic transpose with zero-pad: out[c*rpad + r] (per z-slice) ----------
__global__ void transpose_pad(const float* __restrict__ in, float* __restrict__ out,
                              int rows, int cols, int rpad, long islice, long oslice)
{
    const float* ip = in + (size_t)blockIdx.z * islice;
    float* op = out + (size_t)blockIdx.z * oslice;
    int idx = blockIdx.x * 256 + threadIdx.x;
    if (idx >= cols * rpad) return;
    int c = idx / rpad, r = idx - c * rpad;
    op[idx] = (r < rows) ? ip[(size_t)r * cols + c] : 0.0f;
}

// =======================================================================
// Encoder step. grid 512: x = dir*256 + bg*32 + ng. block 256 = 4 waves.
// Block tile: 32 gate-rows (4g x 8n) x 64 b. Waves k-split K=256 (64 each).
// =======================================================================
__global__ __launch_bounds__(256, 2) void enc_step3(
    const float* __restrict__ sT,   // [SEQL][PT][B]
    const float* __restrict__ WihF, const float* __restrict__ WhhF, const float* __restrict__ bF,
    const float* __restrict__ WihB, const float* __restrict__ WhhB, const float* __restrict__ bB,
    const float* __restrict__ hfin, float* __restrict__ hfout, float* __restrict__ cf,
    const float* __restrict__ hbin, float* __restrict__ hbout, float* __restrict__ cb,
    int t)
{
    __shared__ float lds[8704];   // max(W stage 8192, partials 4*32*68=8704)

    const int tid = threadIdx.x;
    const int x   = blockIdx.x;
    const int ng  = x & 31;
    const int bg  = (x >> 5) & 7;
    const int dir = x >> 8;
    const int n0  = ng * 8;
    const int b0  = bg * 64;

    const float* Whh  = dir ? WhhB : WhhF;
    const float* Wih  = dir ? WihB : WihF;
    const float* bias = dir ? bB   : bF;
    const float* hin  = dir ? hbin : hfin;
    float* hout       = dir ? hbout: hfout;
    float* c          = dir ? cb   : cf;
    const int ts = dir ? (SEQL - 1 - t) : t;

    // ---- stage W: XOR-swizzled by row>>2 ----
    #pragma unroll
    for (int i = 0; i < 8; ++i) {
        const int fidx = i * 256 + tid;            // 0..2047 f4
        const int w  = fidx >> 9;
        const int rem = fidx & 511;
        const int r  = rem >> 4, s5 = rem & 15;
        const int g  = r >> 3, nn = r & 7;
        const float4 wv = *(const float4*)&Whh[(size_t)(g * EH + n0 + nn) * EH + w * 64 + s5 * 4];
        *(float4*)&lds[((w * 32 + r) * 16 + (s5 ^ ((r >> 2) & 7))) * 4] = wv;
    }
    __syncthreads();

    const int lane = tid & 63;
    const int wv   = tid >> 6;
    const int ri   = lane & 7;
    const int bi   = lane >> 3;
    const float* hcol = hin + b0 + bi * 8;

    float acc[4][8];
    #pragma unroll
    for (int m = 0; m < 4; ++m)
        #pragma unroll
        for (int j = 0; j < 8; ++j) acc[m][j] = 0.0f;

    #pragma unroll 4
    for (int j4 = 0; j4 < 16; ++j4) {
        float4 a[4];
        #pragma unroll
        for (int m = 0; m < 4; ++m)
            a[m] = *(const float4*)&lds[((wv * 32 + ri * 4 + m) * 16 + (j4 ^ ri)) * 4];
        float4 blo[4], bhi[4];
        #pragma unroll
        for (int jj = 0; jj < 4; ++jj) {
            const float* hp = hcol + (size_t)(wv * 64 + j4 * 4 + jj) * B;
            blo[jj] = *(const float4*)hp;
            bhi[jj] = *(const float4*)(hp + 4);
        }
        #pragma unroll
        for (int m = 0; m < 4; ++m) {
            FMA8(m, a[m].x, blo[0], bhi[0])
            FMA8(m, a[m].y, blo[1], bhi[1])
            FMA8(m, a[m].z, blo[2], bhi[2])
            FMA8(m, a[m].w, blo[3], bhi[3])
        }
    }
    __syncthreads();

    #pragma unroll
    for (int m = 0; m < 4; ++m) {
        float* pr = &lds[(wv * 32 + ri * 4 + m) * 68 + bi * 8];
        *(float4*)pr       = make_float4(acc[m][0], acc[m][1], acc[m][2], acc[m][3]);
        *(float4*)(pr + 4) = make_float4(acc[m][4], acc[m][5], acc[m][6], acc[m][7]);
    }
    __syncthreads();

    const int nn = tid & 7;
    const int c0 = (tid >> 3) * 2;
    const int bgl = b0 + c0;

    float ps[4][2];
    #pragma unroll
    for (int g = 0; g < 4; ++g) {
        const int r = g * 8 + nn;
        ps[g][0] = lds[r * 68 + c0]     + lds[(32 + r) * 68 + c0]
                 + lds[(64 + r) * 68 + c0] + lds[(96 + r) * 68 + c0];
        ps[g][1] = lds[r * 68 + c0 + 1] + lds[(32 + r) * 68 + c0 + 1]
                 + lds[(64 + r) * 68 + c0 + 1] + lds[(96 + r) * 68 + c0 + 1];
    }

    #pragma unroll
    for (int bb2 = 0; bb2 < 2; ++bb2) {
        const int b = bgl + bb2;
        float gv[4];
        const float x0 = sT[((size_t)ts * PT + 0) * B + b];
        const float x1 = sT[((size_t)ts * PT + 1) * B + b];
        const float x2 = sT[((size_t)ts * PT + 2) * B + b];
        const float x3 = sT[((size_t)ts * PT + 3) * B + b];
        const float x4 = sT[((size_t)ts * PT + 4) * B + b];
        #pragma unroll
        for (int g = 0; g < 4; ++g) {
            const int grow = g * EH + n0 + nn;
            const float* wr = Wih + (size_t)grow * PT;
            float v = ps[g][bb2] + bias[grow];
            v = fmaf(x0, wr[0], v); v = fmaf(x1, wr[1], v); v = fmaf(x2, wr[2], v);
            v = fmaf(x3, wr[3], v); v = fmaf(x4, wr[4], v);
            gv[g] = v;
        }
        const size_t idx = (size_t)(n0 + nn) * B + b;
        const float cv = sigf(gv[1]) * c[idx] + sigf(gv[0]) * tanhf(gv[2]);
        c[idx] = cv;
        hout[idx] = sigf(gv[3]) * tanhf(cv);
    }
}

// =======================================================================
// Decoder step. grid 512: ng = x&63, bg = x>>6 (same-ng blocks share an XCD).
// Block tile: 32 gate-rows x 64 b. Waves k-split K=512 (128 each, 2 chunks).
// =======================================================================
__global__ __launch_bounds__(256, 2) void dec_step3(
    const float* __restrict__ hin, float* __restrict__ hout, float* __restrict__ cT,
    const float* __restrict__ CzT, const float* __restrict__ Whh,
    const float* __restrict__ Wih, const float* __restrict__ prevPt, int t)
{
    __shared__ float lds[16384];  // W stage 64KB >= partials 8704

    const int tid = threadIdx.x;
    const int x   = blockIdx.x;
    const int ng  = x & 63;
    const int bg  = x >> 6;
    const int n0  = ng * 8;
    const int b0  = bg * 64;

    #pragma unroll
    for (int i = 0; i < 16; ++i) {
        const int fidx = i * 256 + tid;            // 0..4095 f4
        const int w   = fidx >> 10;
        const int rem = fidx & 1023;
        const int r   = rem >> 5, s5 = rem & 31;
        const int g   = r >> 3, nn = r & 7;
        const int sl  = (s5 & 16) | ((s5 & 15) ^ ((r >> 2) & 7));
        const float4 wv = *(const float4*)&Whh[(size_t)(g * DH + n0 + nn) * DH + w * 128 + s5 * 4];
        *(float4*)&lds[((w * 32 + r) * 32 + sl) * 4] = wv;
    }
    __syncthreads();

    const int lane = tid & 63;
    const int wv   = tid >> 6;
    const int ri   = lane & 7;
    const int bi   = lane >> 3;
    const float* hcol = hin + b0 + bi * 8;

    float acc[4][8];
    #pragma unroll
    for (int m = 0; m < 4; ++m)
        #pragma unroll
        for (int j = 0; j < 8; ++j) acc[m][j] = 0.0f;

    #pragma unroll
    for (int cc = 0; cc < 2; ++cc) {
        const int kb = wv * 128 + cc * 64;
        #pragma unroll 4
        for (int j4 = 0; j4 < 16; ++j4) {
            float4 a[4];
            #pragma unroll
            for (int m = 0; m < 4; ++m)
                a[m] = *(const float4*)&lds[((wv * 32 + ri * 4 + m) * 32 + cc * 16 + (j4 ^ ri)) * 4];
            float4 blo[4], bhi[4];
            #pragma unroll
            for (int jj = 0; jj < 4; ++jj) {
                const float* hp = hcol + (size_t)(kb + j4 * 4 + jj) * B;
                blo[jj] = *(const float4*)hp;
                bhi[jj] = *(const float4*)(hp + 4);
            }
            #pragma unroll
            for (int m = 0; m < 4; ++m) {
                FMA8(m, a[m].x, blo[0], bhi[0])
                FMA8(m, a[m].y, blo[1], bhi[1])
                FMA8(m, a[m].z, blo[2], bhi[2])
                FMA8(m, a[m].w, blo[3], bhi[3])
            }
        }
    }
    __syncthreads();

    #pragma unroll
    for (int m = 0; m < 4; ++m) {
        float* pr = &lds[(wv * 32 + ri * 4 + m) * 68 + bi * 8];
        *(float4*)pr       = make_float4(acc[m][0], acc[m][1], acc[m][2], acc[m][3]);
        *(float4*)(pr + 4) = make_float4(acc[m][4], acc[m][5], acc[m][6], acc[m][7]);
    }
    __syncthreads();

    const int nn = tid & 7;
    const int c0 = (tid >> 3) * 2;
    const int bgl = b0 + c0;

    float ps[4][2];
    #pragma unroll
    for (int g = 0; g < 4; ++g) {
        const int r = g * 8 + nn;
        ps[g][0] = lds[r * 68 + c0]     + lds[(32 + r) * 68 + c0]
                 + lds[(64 + r) * 68 + c0] + lds[(96 + r) * 68 + c0];
        ps[g][1] = lds[r * 68 + c0 + 1] + lds[(32 + r) * 68 + c0 + 1]
                 + lds[(64 + r) * 68 + c0 + 1] + lds[(96 + r) * 68 + c0 + 1];
    }

    #pragma unroll
    for (int bb2 = 0; bb2 < 2; ++bb2) {
        const int b = bgl + bb2;
        float p0, p1, p2, p3, p4;
        if (t == 0) { p0 = 0.f; p1 = 0.f; p2 = 1.f; p3 = 0.f; p4 = 0.f; }
        else {
            const float* pp = &prevPt[(size_t)b * 5];
            p0 = pp[0]; p1 = pp[1]; p2 = pp[2]; p3 = pp[3]; p4 = pp[4];
        }
        float gv[4];
        #pragma unroll
        for (int g = 0; g < 4; ++g) {
            const int grow = g * DH + n0 + nn;
            const float* wr = Wih + (size_t)grow * 133;
            float v = ps[g][bb2] + CzT[(size_t)grow * B + b];
            v = fmaf(p0, wr[0], v); v = fmaf(p1, wr[1], v); v = fmaf(p2, wr[2], v);
            v = fmaf(p3, wr[3], v); v = fmaf(p4, wr[4], v);
            gv[g] = v;
        }
        const size_t idx = (size_t)(n0 + nn) * B + b;
        const float cv = sigf(gv[1]) * cT[idx] + sigf(gv[0]) * tanhf(gv[2]);
        cT[idx] = cv;
        hout[idx] = sigf(gv[3]) * tanhf(cv);
    }
}

// =======================================================================
// Y = h @ Wdec^T + bdec fused with GMM sampler.
// grid 256 blocks x 256 thr; block = 2 batches x 128 cols, 2-way k-split.
// =======================================================================
__global__ __launch_bounds__(256) void ysamp4(
    const float* __restrict__ hT, const float* __restrict__ WdecT,  // [512][128] zero-padded
    const float* __restrict__ bdec,
    const float* __restrict__ geps, const float* __restrict__ penu,
    float* __restrict__ out, int t)
{
    __shared__ float part[2][2][128];
    __shared__ float Y[2][128];

    const int tid = threadIdx.x;
    const int col = tid & 127;
    const int ks  = tid >> 7;          // 0,1
    const int b0  = blockIdx.x * 2;

    float a0 = 0.f, a1 = 0.f;
    const float* wp = WdecT + (size_t)ks * 256 * 128 + col;
    const float* hp = hT + (size_t)ks * 256 * B + b0;
    #pragma unroll 8
    for (int k = 0; k < 256; ++k) {
        const float w  = wp[(size_t)k * 128];
        const float2 h2 = *(const float2*)(hp + (size_t)k * B);
        a0 = fmaf(w, h2.x, a0);
        a1 = fmaf(w, h2.y, a1);
    }
    part[ks][0][col] = a0;
    part[ks][1][col] = a1;
    __syncthreads();
    if (ks == 0) {
        const float bd = (col < 123) ? bdec[col] : 0.0f;
        Y[0][col] = part[0][0][col] + part[1][0][col] + bd;
        Y[1][col] = part[0][1][col] + part[1][1][col] + bd;
    }
    __syncthreads();

    // sampler: wave 0 -> batch 0, wave 1 -> batch 1; lane m < 20 = mixture m
    if (tid < 128) {
        const int bp   = tid >> 6;
        const int lane = tid & 63;
        const int b    = b0 + bp;
        const float* y = Y[bp];

        const int m = lane;
        float pv = (m < NM) ? y[6 * m] : -1e30f;
        float mm = pv;
        mm = fmaxf(mm, __shfl_xor(mm, 1));  mm = fmaxf(mm, __shfl_xor(mm, 2));
        mm = fmaxf(mm, __shfl_xor(mm, 4));  mm = fmaxf(mm, __shfl_xor(mm, 8));
        mm = fmaxf(mm, __shfl_xor(mm, 16)); mm = fmaxf(mm, __shfl_xor(mm, 32));
        float pe = 0.f, tx = 0.f, ty = 0.f;
        if (m < NM) {
            pe = expf(pv - mm);
            const float mx = y[6 * m + 1], my = y[6 * m + 2];
            const float sx = expf(y[6 * m + 3]), sy = expf(y[6 * m + 4]);
            const float cor = tanhf(y[6 * m + 5]);
            const float l21 = cor / sx;
            const float l22 = sqrtf(fmaxf(sy * sy - l21 * l21, 1e-6f));
            const float* ep = &geps[(((size_t)t * B) + b) * (NM * 2) + 2 * m];
            const float e1 = ep[0], e2 = ep[1];
            tx = pe * fmaf(sx, e1, mx);
            ty = pe * (my + fmaf(l21, e1, l22 * e2));
        }
        XSUM(pe) XSUM(tx) XSUM(ty)
        if (lane == 0) {
            const float q0 = y[120], q1 = y[121], q2 = y[122];
            const float qm = fmaxf(q0, fmaxf(q1, q2));
            const float e0 = expf(q0 - qm), e1q = expf(q1 - qm), e2q = expf(q2 - qm);
            const float qs = e0 + e1q + e2q;
            const float* u = &penu[(((size_t)t * B) + b) * 3];
            float* o = &out[(((size_t)t * B) + b) * 5];
            o[0] = tx / pe;
            o[1] = ty / pe;
            o[2] = (u[0] < e0  / qs) ? 1.f : 0.f;
            o[3] = (u[1] < e1q / qs) ? 1.f : 0.f;
            o[4] = (u[2] < e2q / qs) ? 1.f : 0.f;
        }
    }
}

// ---------------- latent chain ----------------
__global__ __launch_bounds__(256) void latent2(
    const float* __restrict__ hfT, const float* __restrict__ hbT,
    const float* __restrict__ Wmu, const float* __restrict__ bmu,
    const float* __restrict__ Wsig, const float* __restrict__ bsig,
    const float* __restrict__ zepsT, float* __restrict__ zT)
{
    const int lane = threadIdx.x & 63;
    const int wv   = __builtin_amdgcn_readfirstlane(threadIdx.x >> 6);
    const int b    = blockIdx.x * 64 + lane;
    const int n0   = blockIdx.y * 8 + wv * 2;

    float am[2] = {}, as2[2] = {};
    #pragma unroll 4
    for (int k0 = 0; k0 < 2 * EH; k0 += 4) {
        const float* hsrc = (k0 < EH) ? hfT : hbT;
        const int kk = k0 & (EH - 1);
        const float a0 = hsrc[(size_t)(kk + 0) * B + b];
        const float a1 = hsrc[(size_t)(kk + 1) * B + b];
        const float a2 = hsrc[(size_t)(kk + 2) * B + b];
        const float a3 = hsrc[(size_t)(kk + 3) * B + b];
        #pragma unroll
        for (int j = 0; j < 2; ++j) {
            const float4 wm = *(const float4*)&Wmu[((size_t)(n0 + j)) * (2 * EH) + k0];
            const float4 ws = *(const float4*)&Wsig[((size_t)(n0 + j)) * (2 * EH) + k0];
            float u = am[j], v = as2[j];
            u = fmaf(a0, wm.x, u); u = fmaf(a1, wm.y, u); u = fmaf(a2, wm.z, u); u = fmaf(a3, wm.w, u);
            v = fmaf(a0, ws.x, v); v = fmaf(a1, ws.y, v); v = fmaf(a2, ws.z, v); v = fmaf(a3, ws.w, v);
            am[j] = u; as2[j] = v;
        }
    }
    #pragma unroll
    for (int j = 0; j < 2; ++j) {
        const int n = n0 + j;
        const float mu = am[j] + bmu[n];
        const float sg = expf(0.5f * (as2[j] + bsig[n]));
        zT[(size_t)n * B + b] = fmaf(sg, zepsT[(size_t)n * B + b], mu);
    }
}

__global__ __launch_bounds__(256) void h02(
    const float* __restrict__ zT, const float* __restrict__ Wh0,
    const float* __restrict__ bh0, float* __restrict__ hT)
{
    const int lane = threadIdx.x & 63;
    const int wv   = __builtin_amdgcn_readfirstlane(threadIdx.x >> 6);
    const int b    = blockIdx.x * 64 + lane;
    const int n0   = blockIdx.y * 32 + wv * 8;

    float acc[8] = {};
    #pragma unroll 2
    for (int k0 = 0; k0 < ZS; k0 += 4) {
        const float a0 = zT[(size_t)(k0 + 0) * B + b];
        const float a1 = zT[(size_t)(k0 + 1) * B + b];
        const float a2 = zT[(size_t)(k0 + 2) * B + b];
        const float a3 = zT[(size_t)(k0 + 3) * B + b];
        #pragma unroll
        for (int r = 0; r < 8; ++r) {
            const float4 w = *(const float4*)&Wh0[((size_t)(n0 + r)) * ZS + k0];
            float v = acc[r];
            v = fmaf(a0, w.x, v); v = fmaf(a1, w.y, v);
            v = fmaf(a2, w.z, v); v = fmaf(a3, w.w, v);
            acc[r] = v;
        }
    }
    #pragma unroll
    for (int r = 0; r < 8; ++r)
        hT[(size_t)(n0 + r) * B + b] = tanhf(acc[r] + bh0[n0 + r]);
}

__global__ __launch_bounds__(256) void cz2(
    const float* __restrict__ zT, const float* __restrict__ Wih,
    const float* __restrict__ bias, float* __restrict__ CzT)
{
    const int lane = threadIdx.x & 63;
    const int wv   = __builtin_amdgcn_readfirstlane(threadIdx.x >> 6);
    const int b    = blockIdx.x * 64 + lane;
    const int r0   = blockIdx.y * 32 + wv * 8;

    float acc[8] = {};
    #pragma unroll 4
    for (int k = 0; k < ZS; ++k) {
        const float a = zT[(size_t)k * B + b];
        #pragma unroll
        for (int r = 0; r < 8; ++r)
            acc[r] = fmaf(a, Wih[(size_t)(r0 + r) * 133 + 5 + k], acc[r]);
    }
    #pragma unroll
    for (int r = 0; r < 8; ++r)
        CzT[(size_t)(r0 + r) * B + b] = acc[r] + bias[r0 + r];
}

extern "C" void kernel_launch(void* const* d_in, const int* in_sizes, int n_in,
                              void* d_out, int out_size, void* d_ws, size_t ws_size,
                              hipStream_t stream)
{
    (void)in_sizes; (void)n_in; (void)out_size; (void)ws_size;

    const float* s      = (const float*)d_in[0];
    const float* WihF   = (const float*)d_in[1];
    const float* WhhF   = (const float*)d_in[2];
    const float* bF     = (const float*)d_in[3];
    const float* WihB   = (const float*)d_in[4];
    const float* WhhB   = (const float*)d_in[5];
    const float* bB     = (const float*)d_in[6];
    const float* Wmu    = (const float*)d_in[7];
    const float* bmu    = (const float*)d_in[8];
    const float* Wsig   = (const float*)d_in[9];
    const float* bsig   = (const float*)d_in[10];
    const float* Wh0    = (const float*)d_in[11];
    const float* bh0    = (const float*)d_in[12];
    const float* decWih = (const float*)d_in[13];
    const float* decWhh = (const float*)d_in[14];
    const float* decB   = (const float*)d_in[15];
    const float* Wdec   = (const float*)d_in[16];
    const float* bdec   = (const float*)d_in[17];
    const float* zeps   = (const float*)d_in[18];
    const float* geps   = (const float*)d_in[19];
    const float* penu   = (const float*)d_in[20];

    float* out = (float*)d_out;
    float* p   = (float*)d_ws;

    float* hf0  = p; p += 131072;   // zeroed
    float* hb0  = p; p += 131072;   // zeroed
    float* cf   = p; p += 131072;   // zeroed
    float* cb   = p; p += 131072;   // zeroed
    float* cdT  = p; p += 262144;   // zeroed
    float* hf1  = p; p += 131072;
    float* hb1  = p; p += 131072;
    float* hA   = p; p += 262144;
    float* hB   = p; p += 262144;
    float* zT   = p; p += 65536;
    float* CzT  = p; p += 1048576;
    float* zepsT= p; p += 65536;
    float* WdecT= p; p += 65536;
    float* sT   = p; p += 327680;   // [128][5][512]

    hipMemsetAsync((void*)hf0, 0, (size_t)(4 * 131072 + 262144) * sizeof(float), stream);

    transpose_pad<<<dim3(256, 1, 1), 256, 0, stream>>>(zeps, zepsT, B, ZS, B, 0, 0);
    transpose_pad<<<dim3(256, 1, 1), 256, 0, stream>>>(Wdec, WdecT, 123, DH, 128, 0, 0);
    transpose_pad<<<dim3(10, 1, SEQL), 256, 0, stream>>>(s, sT, B, PT, B, (long)B * PT, (long)B * PT);

    for (int t = 0; t < SEQL; ++t) {
        const float* hfin = (t & 1) ? hf1 : hf0;  float* hfout = (t & 1) ? hf0 : hf1;
        const float* hbin = (t & 1) ? hb1 : hb0;  float* hbout = (t & 1) ? hb0 : hb1;
        enc_step3<<<dim3(512), 256, 0, stream>>>(
            sT, WihF, WhhF, bF, WihB, WhhB, bB,
            hfin, hfout, cf, hbin, hbout, cb, t);
    }
    // t=127 (odd) wrote hf0/hb0
    latent2<<<dim3(8, 16), 256, 0, stream>>>(hf0, hb0, Wmu, bmu, Wsig, bsig, zepsT, zT);
    h02<<<dim3(8, 16), 256, 0, stream>>>(zT, Wh0, bh0, hA);
    cz2<<<dim3(8, 64), 256, 0, stream>>>(zT, decWih, decB, CzT);

    for (int t = 0; t < NMAXT; ++t) {
        const float* hin = (t & 1) ? hB : hA;
        float* hout      = (t & 1) ? hA : hB;
        dec_step3<<<dim3(512), 256, 0, stream>>>(
            hin, hout, cdT, CzT, decWhh, decWih,
            t ? (out + (size_t)(t - 1) * B * 5) : out, t);
        ysamp4<<<dim3(256), 256, 0, stream>>>(hout, WdecT, bdec, geps, penu, out, t);
    }
}

// Round 6
// 11073.947 us; speedup vs baseline: 3.4517x; 1.1045x over previous
//
#include <hip/hip_runtime.h>
#include <math.h>

#define B     512
#define SEQL  128
#define PT    5
#define EH    256
#define ZS    128
#define DH    512
#define NM    20
#define NMAXT 256

__device__ __forceinline__ float sigf(float x) { return 1.0f / (1.0f + expf(-x)); }

// acc[m][0..7] += av * {lo,hi}
#define FMA8(m, av, lo, hi)                                                   \
    acc[m][0]=fmaf(av,lo.x,acc[m][0]); acc[m][1]=fmaf(av,lo.y,acc[m][1]);     \
    acc[m][2]=fmaf(av,lo.z,acc[m][2]); acc[m][3]=fmaf(av,lo.w,acc[m][3]);     \
    acc[m][4]=fmaf(av,hi.x,acc[m][4]); acc[m][5]=fmaf(av,hi.y,acc[m][5]);     \
    acc[m][6]=fmaf(av,hi.z,acc[m][6]); acc[m][7]=fmaf(av,hi.w,acc[m][7]);

#define XSUM(v) v += __shfl_xor(v,1); v += __shfl_xor(v,2); v += __shfl_xor(v,4); \
                v += __shfl_xor(v,8); v += __shfl_xor(v,16); v += __shfl_xor(v,32);

// ---------- generic transpose with zero-pad: out[c*rpad + r] (per z-slice) ----------
__global__ void transpose_pad(const float* __restrict__ in, float* __restrict__ out,
                              int rows, int cols, int rpad, long islice, long oslice)
{
    const float* ip = in + (size_t)blockIdx.z * islice;
    float* op = out + (size_t)blockIdx.z * oslice;
    int idx = blockIdx.x * 256 + threadIdx.x;
    if (idx >= cols * rpad) return;
    int c = idx / rpad, r = idx - c * rpad;
    op[idx] = (r < rows) ? ip[(size_t)r * cols + c] : 0.0f;
}

// =======================================================================
// Encoder step. grid 512: x = dir*256 + bg*32 + ng. block 512 = 8 waves.
// Tile: 32 gate-rows (4g x 8n) x 64 b. Waves 8-way k-split (32 k each).
// =======================================================================
__global__ __launch_bounds__(512, 4) void enc_step4(
    const float* __restrict__ sT,   // [SEQL][PT][B]
    const float* __restrict__ WihF, const float* __restrict__ WhhF, const float* __restrict__ bF,
    const float* __restrict__ WihB, const float* __restrict__ WhhB, const float* __restrict__ bB,
    const float* __restrict__ hfin, float* __restrict__ hfout, float* __restrict__ cf,
    const float* __restrict__ hbin, float* __restrict__ hbout, float* __restrict__ cb,
    int t)
{
    __shared__ float lds[17408];   // W stage 8192 floats; partials 8*32*68 = 17408

    const int tid = threadIdx.x;
    const int x   = blockIdx.x;
    const int ng  = x & 31;
    const int bg  = (x >> 5) & 7;
    const int dir = x >> 8;
    const int n0  = ng * 8;
    const int b0  = bg * 64;

    const float* Whh  = dir ? WhhB : WhhF;
    const float* Wih  = dir ? WihB : WihF;
    const float* bias = dir ? bB   : bF;
    const float* hin  = dir ? hbin : hfin;
    float* hout       = dir ? hbout: hfout;
    float* c          = dir ? cb   : cf;
    const int ts = dir ? (SEQL - 1 - t) : t;

    // ---- stage W (32 KB): 2048 f4 / 512 thr = 4 iters, XOR-swizzled ----
    #pragma unroll
    for (int i = 0; i < 4; ++i) {
        const int fidx = i * 512 + tid;            // 0..2047 f4
        const int w   = fidx >> 9;                 // k-chunk of 64
        const int rem = fidx & 511;
        const int r   = rem >> 4, s5 = rem & 15;
        const int g   = r >> 3, nn = r & 7;
        const float4 wv4 = *(const float4*)&Whh[(size_t)(g * EH + n0 + nn) * EH + w * 64 + s5 * 4];
        *(float4*)&lds[((w * 32 + r) * 16 + (s5 ^ ((r >> 2) & 7))) * 4] = wv4;
    }
    __syncthreads();

    const int lane = tid & 63;
    const int wv   = tid >> 6;       // 0..7, k-slice [wv*32, wv*32+32)
    const int ri   = lane & 7;
    const int bi   = lane >> 3;
    const int wq   = wv >> 1;
    const int sb   = (wv & 1) * 8;
    const float* hcol = hin + b0 + bi * 8;

    float acc[4][8];
    #pragma unroll
    for (int m = 0; m < 4; ++m)
        #pragma unroll
        for (int j = 0; j < 8; ++j) acc[m][j] = 0.0f;

    #pragma unroll 2
    for (int j4 = 0; j4 < 8; ++j4) {
        float4 a[4];
        #pragma unroll
        for (int m = 0; m < 4; ++m)
            a[m] = *(const float4*)&lds[((wq * 32 + ri * 4 + m) * 16 + (sb | (j4 ^ ri))) * 4];
        const int kb = wv * 32 + j4 * 4;
        #pragma unroll
        for (int jj = 0; jj < 4; ++jj) {
            const float* hp = hcol + (size_t)(kb + jj) * B;
            const float4 blo = *(const float4*)hp;
            const float4 bhi = *(const float4*)(hp + 4);
            #pragma unroll
            for (int m = 0; m < 4; ++m) {
                const float av = (jj == 0) ? a[m].x : (jj == 1) ? a[m].y : (jj == 2) ? a[m].z : a[m].w;
                FMA8(m, av, blo, bhi)
            }
        }
    }
    __syncthreads();   // done reading W; reuse as partial buffer

    #pragma unroll
    for (int m = 0; m < 4; ++m) {
        float* pr = &lds[(wv * 32 + ri * 4 + m) * 68 + bi * 8];
        *(float4*)pr       = make_float4(acc[m][0], acc[m][1], acc[m][2], acc[m][3]);
        *(float4*)(pr + 4) = make_float4(acc[m][4], acc[m][5], acc[m][6], acc[m][7]);
    }
    __syncthreads();

    // ---- reduce (8-way) + fused LSTM pointwise: 1 cell per thread ----
    const int nn = tid & 7;
    const int c0 = tid >> 3;         // 0..63
    const int b  = b0 + c0;

    float ps[4];
    #pragma unroll
    for (int g = 0; g < 4; ++g) {
        const int r = g * 8 + nn;
        float v = 0.0f;
        #pragma unroll
        for (int w8 = 0; w8 < 8; ++w8) v += lds[(w8 * 32 + r) * 68 + c0];
        ps[g] = v;
    }

    const float x0 = sT[((size_t)ts * PT + 0) * B + b];
    const float x1 = sT[((size_t)ts * PT + 1) * B + b];
    const float x2 = sT[((size_t)ts * PT + 2) * B + b];
    const float x3 = sT[((size_t)ts * PT + 3) * B + b];
    const float x4 = sT[((size_t)ts * PT + 4) * B + b];
    float gv[4];
    #pragma unroll
    for (int g = 0; g < 4; ++g) {
        const int grow = g * EH + n0 + nn;
        const float* wr = Wih + (size_t)grow * PT;
        float v = ps[g] + bias[grow];
        v = fmaf(x0, wr[0], v); v = fmaf(x1, wr[1], v); v = fmaf(x2, wr[2], v);
        v = fmaf(x3, wr[3], v); v = fmaf(x4, wr[4], v);
        gv[g] = v;
    }
    const size_t idx = (size_t)(n0 + nn) * B + b;
    const float cv = sigf(gv[1]) * c[idx] + sigf(gv[0]) * tanhf(gv[2]);
    c[idx] = cv;
    hout[idx] = sigf(gv[3]) * tanhf(cv);
}

// =======================================================================
// Decoder step. grid 512: ng = x&63, bg = x>>6. block 512 = 8 waves.
// Tile: 32 gate-rows x 64 b. Waves 8-way k-split (64 k each).
// =======================================================================
__global__ __launch_bounds__(512, 4) void dec_step4(
    const float* __restrict__ hin, float* __restrict__ hout, float* __restrict__ cT,
    const float* __restrict__ CzT, const float* __restrict__ Whh,
    const float* __restrict__ Wih, const float* __restrict__ prevPt, int t)
{
    __shared__ float lds[17408];  // W stage 16384; partials 17408

    const int tid = threadIdx.x;
    const int x   = blockIdx.x;
    const int ng  = x & 63;
    const int bg  = x >> 6;
    const int n0  = ng * 8;
    const int b0  = bg * 64;

    // ---- stage W (64 KB): 4096 f4 / 512 thr = 8 iters ----
    #pragma unroll
    for (int i = 0; i < 8; ++i) {
        const int fidx = i * 512 + tid;            // 0..4095 f4
        const int w   = fidx >> 10;                // k-chunk of 128
        const int rem = fidx & 1023;
        const int r   = rem >> 5, s5 = rem & 31;
        const int g   = r >> 3, nn = r & 7;
        const int sl  = (s5 & 16) | ((s5 & 15) ^ ((r >> 2) & 7));
        const float4 wv4 = *(const float4*)&Whh[(size_t)(g * DH + n0 + nn) * DH + w * 128 + s5 * 4];
        *(float4*)&lds[((w * 32 + r) * 32 + sl) * 4] = wv4;
    }
    __syncthreads();

    const int lane = tid & 63;
    const int wv   = tid >> 6;       // 0..7, k-slice [wv*64, wv*64+64)
    const int ri   = lane & 7;
    const int bi   = lane >> 3;
    const int wq   = wv >> 1;
    const int sb   = (wv & 1) * 16;
    const float* hcol = hin + b0 + bi * 8;

    float acc[4][8];
    #pragma unroll
    for (int m = 0; m < 4; ++m)
        #pragma unroll
        for (int j = 0; j < 8; ++j) acc[m][j] = 0.0f;

    #pragma unroll 2
    for (int j4 = 0; j4 < 16; ++j4) {
        float4 a[4];
        #pragma unroll
        for (int m = 0; m < 4; ++m)
            a[m] = *(const float4*)&lds[((wq * 32 + ri * 4 + m) * 32 + (sb | (j4 ^ ri))) * 4];
        const int kb = wv * 64 + j4 * 4;
        #pragma unroll
        for (int jj = 0; jj < 4; ++jj) {
            const float* hp = hcol + (size_t)(kb + jj) * B;
            const float4 blo = *(const float4*)hp;
            const float4 bhi = *(const float4*)(hp + 4);
            #pragma unroll
            for (int m = 0; m < 4; ++m) {
                const float av = (jj == 0) ? a[m].x : (jj == 1) ? a[m].y : (jj == 2) ? a[m].z : a[m].w;
                FMA8(m, av, blo, bhi)
            }
        }
    }
    __syncthreads();

    #pragma unroll
    for (int m = 0; m < 4; ++m) {
        float* pr = &lds[(wv * 32 + ri * 4 + m) * 68 + bi * 8];
        *(float4*)pr       = make_float4(acc[m][0], acc[m][1], acc[m][2], acc[m][3]);
        *(float4*)(pr + 4) = make_float4(acc[m][4], acc[m][5], acc[m][6], acc[m][7]);
    }
    __syncthreads();

    // ---- reduce (8-way) + pointwise: 1 cell per thread ----
    const int nn = tid & 7;
    const int c0 = tid >> 3;
    const int b  = b0 + c0;

    float ps[4];
    #pragma unroll
    for (int g = 0; g < 4; ++g) {
        const int r = g * 8 + nn;
        float v = 0.0f;
        #pragma unroll
        for (int w8 = 0; w8 < 8; ++w8) v += lds[(w8 * 32 + r) * 68 + c0];
        ps[g] = v;
    }

    float p0, p1, p2, p3, p4;
    if (t == 0) { p0 = 0.f; p1 = 0.f; p2 = 1.f; p3 = 0.f; p4 = 0.f; }
    else {
        const float* pp = &prevPt[(size_t)b * 5];
        p0 = pp[0]; p1 = pp[1]; p2 = pp[2]; p3 = pp[3]; p4 = pp[4];
    }
    float gv[4];
    #pragma unroll
    for (int g = 0; g < 4; ++g) {
        const int grow = g * DH + n0 + nn;
        const float* wr = Wih + (size_t)grow * 133;
        float v = ps[g] + CzT[(size_t)grow * B + b];
        v = fmaf(p0, wr[0], v); v = fmaf(p1, wr[1], v); v = fmaf(p2, wr[2], v);
        v = fmaf(p3, wr[3], v); v = fmaf(p4, wr[4], v);
        gv[g] = v;
    }
    const size_t idx = (size_t)(n0 + nn) * B + b;
    const float cv = sigf(gv[1]) * cT[idx] + sigf(gv[0]) * tanhf(gv[2]);
    cT[idx] = cv;
    hout[idx] = sigf(gv[3]) * tanhf(cv);
}

// =======================================================================
// Y = h @ Wdec^T + bdec fused with GMM sampler.
// grid 512 blocks x 512 thr; block = 1 batch x 128 cols, 4-way k-split.
// =======================================================================
__global__ __launch_bounds__(512) void ysamp5(
    const float* __restrict__ hT, const float* __restrict__ WdecT,  // [512][128] zero-padded
    const float* __restrict__ bdec,
    const float* __restrict__ geps, const float* __restrict__ penu,
    float* __restrict__ out, int t)
{
    __shared__ float part[4][128];
    __shared__ float Y[128];

    const int tid = threadIdx.x;
    const int col = tid & 127;
    const int ks  = tid >> 7;          // 0..3, k-slice 128
    const int b   = blockIdx.x;

    float a0 = 0.f;
    const float* wp = WdecT + (size_t)ks * 128 * 128 + col;
    const float* hp = hT + (size_t)ks * 128 * B + b;
    #pragma unroll 8
    for (int k = 0; k < 128; ++k)
        a0 = fmaf(wp[(size_t)k * 128], hp[(size_t)k * B], a0);
    part[ks][col] = a0;
    __syncthreads();
    if (ks == 0)
        Y[col] = part[0][col] + part[1][col] + part[2][col] + part[3][col]
               + ((col < 123) ? bdec[col] : 0.0f);
    __syncthreads();

    // sampler: wave 0, lane m < 20 = mixture m
    if (tid < 64) {
        const int lane = tid;
        const float* y = Y;
        const int m = lane;
        float pv = (m < NM) ? y[6 * m] : -1e30f;
        float mm = pv;
        mm = fmaxf(mm, __shfl_xor(mm, 1));  mm = fmaxf(mm, __shfl_xor(mm, 2));
        mm = fmaxf(mm, __shfl_xor(mm, 4));  mm = fmaxf(mm, __shfl_xor(mm, 8));
        mm = fmaxf(mm, __shfl_xor(mm, 16)); mm = fmaxf(mm, __shfl_xor(mm, 32));
        float pe = 0.f, tx = 0.f, ty = 0.f;
        if (m < NM) {
            pe = expf(pv - mm);
            const float mx = y[6 * m + 1], my = y[6 * m + 2];
            const float sx = expf(y[6 * m + 3]), sy = expf(y[6 * m + 4]);
            const float cor = tanhf(y[6 * m + 5]);
            const float l21 = cor / sx;
            const float l22 = sqrtf(fmaxf(sy * sy - l21 * l21, 1e-6f));
            const float* ep = &geps[(((size_t)t * B) + b) * (NM * 2) + 2 * m];
            const float e1 = ep[0], e2 = ep[1];
            tx = pe * fmaf(sx, e1, mx);
            ty = pe * (my + fmaf(l21, e1, l22 * e2));
        }
        XSUM(pe) XSUM(tx) XSUM(ty)
        if (lane == 0) {
            const float q0 = y[120], q1 = y[121], q2 = y[122];
            const float qm = fmaxf(q0, fmaxf(q1, q2));
            const float e0 = expf(q0 - qm), e1q = expf(q1 - qm), e2q = expf(q2 - qm);
            const float qs = e0 + e1q + e2q;
            const float* u = &penu[(((size_t)t * B) + b) * 3];
            float* o = &out[(((size_t)t * B) + b) * 5];
            o[0] = tx / pe;
            o[1] = ty / pe;
            o[2] = (u[0] < e0  / qs) ? 1.f : 0.f;
            o[3] = (u[1] < e1q / qs) ? 1.f : 0.f;
            o[4] = (u[2] < e2q / qs) ? 1.f : 0.f;
        }
    }
}

// ---------------- latent chain ----------------
__global__ __launch_bounds__(256) void latent2(
    const float* __restrict__ hfT, const float* __restrict__ hbT,
    const float* __restrict__ Wmu, const float* __restrict__ bmu,
    const float* __restrict__ Wsig, const float* __restrict__ bsig,
    const float* __restrict__ zepsT, float* __restrict__ zT)
{
    const int lane = threadIdx.x & 63;
    const int wv   = __builtin_amdgcn_readfirstlane(threadIdx.x >> 6);
    const int b    = blockIdx.x * 64 + lane;
    const int n0   = blockIdx.y * 8 + wv * 2;

    float am[2] = {}, as2[2] = {};
    #pragma unroll 4
    for (int k0 = 0; k0 < 2 * EH; k0 += 4) {
        const float* hsrc = (k0 < EH) ? hfT : hbT;
        const int kk = k0 & (EH - 1);
        const float a0 = hsrc[(size_t)(kk + 0) * B + b];
        const float a1 = hsrc[(size_t)(kk + 1) * B + b];
        const float a2 = hsrc[(size_t)(kk + 2) * B + b];
        const float a3 = hsrc[(size_t)(kk + 3) * B + b];
        #pragma unroll
        for (int j = 0; j < 2; ++j) {
            const float4 wm = *(const float4*)&Wmu[((size_t)(n0 + j)) * (2 * EH) + k0];
            const float4 ws = *(const float4*)&Wsig[((size_t)(n0 + j)) * (2 * EH) + k0];
            float u = am[j], v = as2[j];
            u = fmaf(a0, wm.x, u); u = fmaf(a1, wm.y, u); u = fmaf(a2, wm.z, u); u = fmaf(a3, wm.w, u);
            v = fmaf(a0, ws.x, v); v = fmaf(a1, ws.y, v); v = fmaf(a2, ws.z, v); v = fmaf(a3, ws.w, v);
            am[j] = u; as2[j] = v;
        }
    }
    #pragma unroll
    for (int j = 0; j < 2; ++j) {
        const int n = n0 + j;
        const float mu = am[j] + bmu[n];
        const float sg = expf(0.5f * (as2[j] + bsig[n]));
        zT[(size_t)n * B + b] = fmaf(sg, zepsT[(size_t)n * B + b], mu);
    }
}

__global__ __launch_bounds__(256) void h02(
    const float* __restrict__ zT, const float* __restrict__ Wh0,
    const float* __restrict__ bh0, float* __restrict__ hT)
{
    const int lane = threadIdx.x & 63;
    const int wv   = __builtin_amdgcn_readfirstlane(threadIdx.x >> 6);
    const int b    = blockIdx.x * 64 + lane;
    const int n0   = blockIdx.y * 32 + wv * 8;

    float acc[8] = {};
    #pragma unroll 2
    for (int k0 = 0; k0 < ZS; k0 += 4) {
        const float a0 = zT[(size_t)(k0 + 0) * B + b];
        const float a1 = zT[(size_t)(k0 + 1) * B + b];
        const float a2 = zT[(size_t)(k0 + 2) * B + b];
        const float a3 = zT[(size_t)(k0 + 3) * B + b];
        #pragma unroll
        for (int r = 0; r < 8; ++r) {
            const float4 w = *(const float4*)&Wh0[((size_t)(n0 + r)) * ZS + k0];
            float v = acc[r];
            v = fmaf(a0, w.x, v); v = fmaf(a1, w.y, v);
            v = fmaf(a2, w.z, v); v = fmaf(a3, w.w, v);
            acc[r] = v;
        }
    }
    #pragma unroll
    for (int r = 0; r < 8; ++r)
        hT[(size_t)(n0 + r) * B + b] = tanhf(acc[r] + bh0[n0 + r]);
}

__global__ __launch_bounds__(256) void cz2(
    const float* __restrict__ zT, const float* __restrict__ Wih,
    const float* __restrict__ bias, float* __restrict__ CzT)
{
    const int lane = threadIdx.x & 63;
    const int wv   = __builtin_amdgcn_readfirstlane(threadIdx.x >> 6);
    const int b    = blockIdx.x * 64 + lane;
    const int r0   = blockIdx.y * 32 + wv * 8;

    float acc[8] = {};
    #pragma unroll 4
    for (int k = 0; k < ZS; ++k) {
        const float a = zT[(size_t)k * B + b];
        #pragma unroll
        for (int r = 0; r < 8; ++r)
            acc[r] = fmaf(a, Wih[(size_t)(r0 + r) * 133 + 5 + k], acc[r]);
    }
    #pragma unroll
    for (int r = 0; r < 8; ++r)
        CzT[(size_t)(r0 + r) * B + b] = acc[r] + bias[r0 + r];
}

extern "C" void kernel_launch(void* const* d_in, const int* in_sizes, int n_in,
                              void* d_out, int out_size, void* d_ws, size_t ws_size,
                              hipStream_t stream)
{
    (void)in_sizes; (void)n_in; (void)out_size; (void)ws_size;

    const float* s      = (const float*)d_in[0];
    const float* WihF   = (const float*)d_in[1];
    const float* WhhF   = (const float*)d_in[2];
    const float* bF     = (const float*)d_in[3];
    const float* WihB   = (const float*)d_in[4];
    const float* WhhB   = (const float*)d_in[5];
    const float* bB     = (const float*)d_in[6];
    const float* Wmu    = (const float*)d_in[7];
    const float* bmu    = (const float*)d_in[8];
    const float* Wsig   = (const float*)d_in[9];
    const float* bsig   = (const float*)d_in[10];
    const float* Wh0    = (const float*)d_in[11];
    const float* bh0    = (const float*)d_in[12];
    const float* decWih = (const float*)d_in[13];
    const float* decWhh = (const float*)d_in[14];
    const float* decB   = (const float*)d_in[15];
    const float* Wdec   = (const float*)d_in[16];
    const float* bdec   = (const float*)d_in[17];
    const float* zeps   = (const float*)d_in[18];
    const float* geps   = (const float*)d_in[19];
    const float* penu   = (const float*)d_in[20];

    float* out = (float*)d_out;
    float* p   = (float*)d_ws;

    float* hf0  = p; p += 131072;   // zeroed
    float* hb0  = p; p += 131072;   // zeroed
    float* cf   = p; p += 131072;   // zeroed
    float* cb   = p; p += 131072;   // zeroed
    float* cdT  = p; p += 262144;   // zeroed
    float* hf1  = p; p += 131072;
    float* hb1  = p; p += 131072;
    float* hA   = p; p += 262144;
    float* hB   = p; p += 262144;
    float* zT   = p; p += 65536;
    float* CzT  = p; p += 1048576;
    float* zepsT= p; p += 65536;
    float* WdecT= p; p += 65536;
    float* sT   = p; p += 327680;   // [128][5][512]

    hipMemsetAsync((void*)hf0, 0, (size_t)(4 * 131072 + 262144) * sizeof(float), stream);

    transpose_pad<<<dim3(256, 1, 1), 256, 0, stream>>>(zeps, zepsT, B, ZS, B, 0, 0);
    transpose_pad<<<dim3(256, 1, 1), 256, 0, stream>>>(Wdec, WdecT, 123, DH, 128, 0, 0);
    transpose_pad<<<dim3(10, 1, SEQL), 256, 0, stream>>>(s, sT, B, PT, B, (long)B * PT, (long)B * PT);

    for (int t = 0; t < SEQL; ++t) {
        const float* hfin = (t & 1) ? hf1 : hf0;  float* hfout = (t & 1) ? hf0 : hf1;
        const float* hbin = (t & 1) ? hb1 : hb0;  float* hbout = (t & 1) ? hb0 : hb1;
        enc_step4<<<dim3(512), 512, 0, stream>>>(
            sT, WihF, WhhF, bF, WihB, WhhB, bB,
            hfin, hfout, cf, hbin, hbout, cb, t);
    }
    // t=127 (odd) wrote hf0/hb0
    latent2<<<dim3(8, 16), 256, 0, stream>>>(hf0, hb0, Wmu, bmu, Wsig, bsig, zepsT, zT);
    h02<<<dim3(8, 16), 256, 0, stream>>>(zT, Wh0, bh0, hA);
    cz2<<<dim3(8, 64), 256, 0, stream>>>(zT, decWih, decB, CzT);

    for (int t = 0; t < NMAXT; ++t) {
        const float* hin = (t & 1) ? hB : hA;
        float* hout      = (t & 1) ? hA : hB;
        dec_step4<<<dim3(512), 512, 0, stream>>>(
            hin, hout, cdT, CzT, decWhh, decWih,
            t ? (out + (size_t)(t - 1) * B * 5) : out, t);
        ysamp5<<<dim3(512), 512, 0, stream>>>(hout, WdecT, bdec, geps, penu, out, t);
    }
}

// Round 7
// 9941.953 us; speedup vs baseline: 3.8447x; 1.1139x over previous
//
#include <hip/hip_runtime.h>
#include <math.h>

#define B     512
#define SEQL  128
#define PT    5
#define EH    256
#define ZS    128
#define DH    512
#define NM    20
#define NMAXT 256

__device__ __forceinline__ float sigf(float x) { return 1.0f / (1.0f + expf(-x)); }

// acc[m][0..7] += av * {lo,hi}
#define FMA8(m, av, lo, hi)                                                   \
    acc[m][0]=fmaf(av,lo.x,acc[m][0]); acc[m][1]=fmaf(av,lo.y,acc[m][1]);     \
    acc[m][2]=fmaf(av,lo.z,acc[m][2]); acc[m][3]=fmaf(av,lo.w,acc[m][3]);     \
    acc[m][4]=fmaf(av,hi.x,acc[m][4]); acc[m][5]=fmaf(av,hi.y,acc[m][5]);     \
    acc[m][6]=fmaf(av,hi.z,acc[m][6]); acc[m][7]=fmaf(av,hi.w,acc[m][7]);

#define XSUM(v) v += __shfl_xor(v,1); v += __shfl_xor(v,2); v += __shfl_xor(v,4); \
                v += __shfl_xor(v,8); v += __shfl_xor(v,16); v += __shfl_xor(v,32);

// ---------- generic transpose with zero-pad: out[c*rpad + r] (per z-slice) ----------
__global__ void transpose_pad(const float* __restrict__ in, float* __restrict__ out,
                              int rows, int cols, int rpad, long islice, long oslice)
{
    const float* ip = in + (size_t)blockIdx.z * islice;
    float* op = out + (size_t)blockIdx.z * oslice;
    int idx = blockIdx.x * 256 + threadIdx.x;
    if (idx >= cols * rpad) return;
    int c = idx / rpad, r = idx - c * rpad;
    op[idx] = (r < rows) ? ip[(size_t)r * cols + c] : 0.0f;
}

// =======================================================================
// Encoder step. grid 512: x = dir*256 + bg*32 + ng. block 512 = 8 waves.
// Tile: 32 gate-rows (4g x 8n) x 64 b. Waves 8-way k-split (32 k each).
// =======================================================================
__global__ __launch_bounds__(512, 4) void enc_step5(
    const float* __restrict__ sT,   // [SEQL][PT][B]
    const float* __restrict__ WihF, const float* __restrict__ WhhF, const float* __restrict__ bF,
    const float* __restrict__ WihB, const float* __restrict__ WhhB, const float* __restrict__ bB,
    const float* __restrict__ hfin, float* __restrict__ hfout, float* __restrict__ cf,
    const float* __restrict__ hbin, float* __restrict__ hbout, float* __restrict__ cb,
    int t)
{
    __shared__ float lds[17408];   // W stage 8192 floats; partials 8*32*68 = 17408

    const int tid = threadIdx.x;
    const int x   = blockIdx.x;
    const int ng  = x & 31;
    const int bg  = (x >> 5) & 7;
    const int dir = x >> 8;
    const int n0  = ng * 8;
    const int b0  = bg * 64;

    const float* Whh  = dir ? WhhB : WhhF;
    const float* Wih  = dir ? WihB : WihF;
    const float* bias = dir ? bB   : bF;
    const float* hin  = dir ? hbin : hfin;
    float* hout       = dir ? hbout: hfout;
    float* c          = dir ? cb   : cf;
    const int ts = dir ? (SEQL - 1 - t) : t;

    // ---- pointwise-phase prefetch (resolves under G compute) ----
    const int pn = tid & 7;
    const int pc = tid >> 3;         // 0..63
    const int pb = b0 + pc;
    const size_t pidx = (size_t)(n0 + pn) * B + pb;
    const float cold = c[pidx];
    const float x0 = sT[((size_t)ts * PT + 0) * B + pb];
    const float x1 = sT[((size_t)ts * PT + 1) * B + pb];
    const float x2 = sT[((size_t)ts * PT + 2) * B + pb];
    const float x3 = sT[((size_t)ts * PT + 3) * B + pb];
    const float x4 = sT[((size_t)ts * PT + 4) * B + pb];

    // ---- stage W (32 KB): 2048 f4 / 512 thr = 4 iters, XOR-swizzled ----
    #pragma unroll
    for (int i = 0; i < 4; ++i) {
        const int fidx = i * 512 + tid;            // 0..2047 f4
        const int w   = fidx >> 9;                 // k-chunk of 64
        const int rem = fidx & 511;
        const int r   = rem >> 4, s5 = rem & 15;
        const int g   = r >> 3, nn = r & 7;
        const float4 wv4 = *(const float4*)&Whh[(size_t)(g * EH + n0 + nn) * EH + w * 64 + s5 * 4];
        *(float4*)&lds[((w * 32 + r) * 16 + (s5 ^ ((r >> 2) & 7))) * 4] = wv4;
    }
    __syncthreads();

    const int lane = tid & 63;
    const int wv   = tid >> 6;       // 0..7, k-slice [wv*32, wv*32+32)
    const int ri   = lane & 7;
    const int bi   = lane >> 3;
    const int wq   = wv >> 1;
    const int sb   = (wv & 1) * 8;
    const float* hcol = hin + b0 + bi * 8;

    float acc[4][8];
    #pragma unroll
    for (int m = 0; m < 4; ++m)
        #pragma unroll
        for (int j = 0; j < 8; ++j) acc[m][j] = 0.0f;

    #pragma unroll 2
    for (int j4 = 0; j4 < 8; ++j4) {
        float4 a[4];
        #pragma unroll
        for (int m = 0; m < 4; ++m)
            a[m] = *(const float4*)&lds[((wq * 32 + ri * 4 + m) * 16 + (sb | (j4 ^ ri))) * 4];
        const int kb = wv * 32 + j4 * 4;
        #pragma unroll
        for (int jj = 0; jj < 4; ++jj) {
            const float* hp = hcol + (size_t)(kb + jj) * B;
            const float4 blo = *(const float4*)hp;
            const float4 bhi = *(const float4*)(hp + 4);
            #pragma unroll
            for (int m = 0; m < 4; ++m) {
                const float av = (jj == 0) ? a[m].x : (jj == 1) ? a[m].y : (jj == 2) ? a[m].z : a[m].w;
                FMA8(m, av, blo, bhi)
            }
        }
    }
    __syncthreads();   // done reading W; reuse as partial buffer

    #pragma unroll
    for (int m = 0; m < 4; ++m) {
        float* pr = &lds[(wv * 32 + ri * 4 + m) * 68 + bi * 8];
        *(float4*)pr       = make_float4(acc[m][0], acc[m][1], acc[m][2], acc[m][3]);
        *(float4*)(pr + 4) = make_float4(acc[m][4], acc[m][5], acc[m][6], acc[m][7]);
    }
    __syncthreads();

    // ---- reduce (8-way) + fused LSTM pointwise: 1 cell per thread ----
    float ps[4];
    #pragma unroll
    for (int g = 0; g < 4; ++g) {
        const int r = g * 8 + pn;
        float v = 0.0f;
        #pragma unroll
        for (int w8 = 0; w8 < 8; ++w8) v += lds[(w8 * 32 + r) * 68 + pc];
        ps[g] = v;
    }

    float gv[4];
    #pragma unroll
    for (int g = 0; g < 4; ++g) {
        const int grow = g * EH + n0 + pn;
        const float* wr = Wih + (size_t)grow * PT;
        float v = ps[g] + bias[grow];
        v = fmaf(x0, wr[0], v); v = fmaf(x1, wr[1], v); v = fmaf(x2, wr[2], v);
        v = fmaf(x3, wr[3], v); v = fmaf(x4, wr[4], v);
        gv[g] = v;
    }
    const float cv = sigf(gv[1]) * cold + sigf(gv[0]) * tanhf(gv[2]);
    c[pidx] = cv;
    hout[pidx] = sigf(gv[3]) * tanhf(cv);
}

// =======================================================================
// Decoder step. grid 512: ng = x&63, bg = x>>6. block 512 = 8 waves.
// Tile: 32 gate-rows x 64 b. Waves 8-way k-split (64 k each).
// =======================================================================
__global__ __launch_bounds__(512, 4) void dec_step5(
    const float* __restrict__ hin, float* __restrict__ hout, float* __restrict__ cT,
    const float* __restrict__ CzT, const float* __restrict__ Whh,
    const float* __restrict__ Wih, const float* __restrict__ prevPt, int t)
{
    __shared__ float lds[17408];  // W stage 16384; partials 17408

    const int tid = threadIdx.x;
    const int x   = blockIdx.x;
    const int ng  = x & 63;
    const int bg  = x >> 6;
    const int n0  = ng * 8;
    const int b0  = bg * 64;

    // ---- pointwise-phase prefetch ----
    const int pn = tid & 7;
    const int pc = tid >> 3;
    const int pb = b0 + pc;
    const size_t pidx = (size_t)(n0 + pn) * B + pb;
    const float cold = cT[pidx];
    float p0, p1, p2, p3, p4;
    if (t == 0) { p0 = 0.f; p1 = 0.f; p2 = 1.f; p3 = 0.f; p4 = 0.f; }
    else {
        const float* pp = &prevPt[(size_t)pb * 5];
        p0 = pp[0]; p1 = pp[1]; p2 = pp[2]; p3 = pp[3]; p4 = pp[4];
    }
    float cz[4];
    #pragma unroll
    for (int g = 0; g < 4; ++g)
        cz[g] = CzT[(size_t)(g * DH + n0 + pn) * B + pb];

    // ---- stage W (64 KB): 4096 f4 / 512 thr = 8 iters ----
    #pragma unroll
    for (int i = 0; i < 8; ++i) {
        const int fidx = i * 512 + tid;            // 0..4095 f4
        const int w   = fidx >> 10;                // k-chunk of 128
        const int rem = fidx & 1023;
        const int r   = rem >> 5, s5 = rem & 31;
        const int g   = r >> 3, nn = r & 7;
        const int sl  = (s5 & 16) | ((s5 & 15) ^ ((r >> 2) & 7));
        const float4 wv4 = *(const float4*)&Whh[(size_t)(g * DH + n0 + nn) * DH + w * 128 + s5 * 4];
        *(float4*)&lds[((w * 32 + r) * 32 + sl) * 4] = wv4;
    }
    __syncthreads();

    const int lane = tid & 63;
    const int wv   = tid >> 6;       // 0..7, k-slice [wv*64, wv*64+64)
    const int ri   = lane & 7;
    const int bi   = lane >> 3;
    const int wq   = wv >> 1;
    const int sb   = (wv & 1) * 16;
    const float* hcol = hin + b0 + bi * 8;

    float acc[4][8];
    #pragma unroll
    for (int m = 0; m < 4; ++m)
        #pragma unroll
        for (int j = 0; j < 8; ++j) acc[m][j] = 0.0f;

    #pragma unroll 2
    for (int j4 = 0; j4 < 16; ++j4) {
        float4 a[4];
        #pragma unroll
        for (int m = 0; m < 4; ++m)
            a[m] = *(const float4*)&lds[((wq * 32 + ri * 4 + m) * 32 + (sb | (j4 ^ ri))) * 4];
        const int kb = wv * 64 + j4 * 4;
        #pragma unroll
        for (int jj = 0; jj < 4; ++jj) {
            const float* hp = hcol + (size_t)(kb + jj) * B;
            const float4 blo = *(const float4*)hp;
            const float4 bhi = *(const float4*)(hp + 4);
            #pragma unroll
            for (int m = 0; m < 4; ++m) {
                const float av = (jj == 0) ? a[m].x : (jj == 1) ? a[m].y : (jj == 2) ? a[m].z : a[m].w;
                FMA8(m, av, blo, bhi)
            }
        }
    }
    __syncthreads();

    #pragma unroll
    for (int m = 0; m < 4; ++m) {
        float* pr = &lds[(wv * 32 + ri * 4 + m) * 68 + bi * 8];
        *(float4*)pr       = make_float4(acc[m][0], acc[m][1], acc[m][2], acc[m][3]);
        *(float4*)(pr + 4) = make_float4(acc[m][4], acc[m][5], acc[m][6], acc[m][7]);
    }
    __syncthreads();

    // ---- reduce (8-way) + pointwise: 1 cell per thread ----
    float ps[4];
    #pragma unroll
    for (int g = 0; g < 4; ++g) {
        const int r = g * 8 + pn;
        float v = 0.0f;
        #pragma unroll
        for (int w8 = 0; w8 < 8; ++w8) v += lds[(w8 * 32 + r) * 68 + pc];
        ps[g] = v;
    }

    float gv[4];
    #pragma unroll
    for (int g = 0; g < 4; ++g) {
        const int grow = g * DH + n0 + pn;
        const float* wr = Wih + (size_t)grow * 133;
        float v = ps[g] + cz[g];
        v = fmaf(p0, wr[0], v); v = fmaf(p1, wr[1], v); v = fmaf(p2, wr[2], v);
        v = fmaf(p3, wr[3], v); v = fmaf(p4, wr[4], v);
        gv[g] = v;
    }
    const float cv = sigf(gv[1]) * cold + sigf(gv[0]) * tanhf(gv[2]);
    cT[pidx] = cv;
    hout[pidx] = sigf(gv[3]) * tanhf(cv);
}

// =======================================================================
// Y = h @ Wdec^T + bdec fused with GMM sampler.
// grid 128 blocks x 512 thr; block = 4 batches x 128 cols, 4-way k-split.
// h staged into LDS (coalesced), W reads coalesced & shared over 4 batches.
// =======================================================================
__global__ __launch_bounds__(512) void ysamp6(
    const float* __restrict__ hT, const float* __restrict__ WdecT,  // [512][128] zero-padded
    const float* __restrict__ bdec,
    const float* __restrict__ geps, const float* __restrict__ penu,
    float* __restrict__ out, int t)
{
    __shared__ float h_s[512][4];
    __shared__ float part[4][128][4];
    __shared__ float Y[4][128];

    const int tid = threadIdx.x;
    const int col = tid & 127;
    const int ks  = tid >> 7;          // 0..3, k-slice 128
    const int b0  = blockIdx.x * 4;

    // stage h[512][b0..b0+4): 1 float4 per thread, fully coalesced
    *(float4*)&h_s[tid][0] = *(const float4*)&hT[(size_t)tid * B + b0];
    __syncthreads();

    float a0 = 0.f, a1 = 0.f, a2 = 0.f, a3 = 0.f;
    const float* wp = WdecT + (size_t)ks * 128 * 128 + col;
    #pragma unroll 8
    for (int k = 0; k < 128; ++k) {
        const float w = wp[(size_t)k * 128];
        const float4 hq = *(const float4*)&h_s[ks * 128 + k][0];
        a0 = fmaf(w, hq.x, a0); a1 = fmaf(w, hq.y, a1);
        a2 = fmaf(w, hq.z, a2); a3 = fmaf(w, hq.w, a3);
    }
    part[ks][col][0] = a0; part[ks][col][1] = a1;
    part[ks][col][2] = a2; part[ks][col][3] = a3;
    __syncthreads();
    if (ks == 0) {
        const float bd = (col < 123) ? bdec[col] : 0.0f;
        #pragma unroll
        for (int j = 0; j < 4; ++j)
            Y[j][col] = part[0][col][j] + part[1][col][j] + part[2][col][j]
                      + part[3][col][j] + bd;
    }
    __syncthreads();

    // sampler: wave j -> batch b0+j; lane m < 20 = mixture m
    if (tid < 256) {
        const int bp   = tid >> 6;
        const int lane = tid & 63;
        const int b    = b0 + bp;
        const float* y = Y[bp];
        const int m = lane;
        float pv = (m < NM) ? y[6 * m] : -1e30f;
        float mm = pv;
        mm = fmaxf(mm, __shfl_xor(mm, 1));  mm = fmaxf(mm, __shfl_xor(mm, 2));
        mm = fmaxf(mm, __shfl_xor(mm, 4));  mm = fmaxf(mm, __shfl_xor(mm, 8));
        mm = fmaxf(mm, __shfl_xor(mm, 16)); mm = fmaxf(mm, __shfl_xor(mm, 32));
        float pe = 0.f, tx = 0.f, ty = 0.f;
        if (m < NM) {
            pe = expf(pv - mm);
            const float mx = y[6 * m + 1], my = y[6 * m + 2];
            const float sx = expf(y[6 * m + 3]), sy = expf(y[6 * m + 4]);
            const float cor = tanhf(y[6 * m + 5]);
            const float l21 = cor / sx;
            const float l22 = sqrtf(fmaxf(sy * sy - l21 * l21, 1e-6f));
            const float* ep = &geps[(((size_t)t * B) + b) * (NM * 2) + 2 * m];
            const float e1 = ep[0], e2 = ep[1];
            tx = pe * fmaf(sx, e1, mx);
            ty = pe * (my + fmaf(l21, e1, l22 * e2));
        }
        XSUM(pe) XSUM(tx) XSUM(ty)
        if (lane == 0) {
            const float q0 = y[120], q1 = y[121], q2 = y[122];
            const float qm = fmaxf(q0, fmaxf(q1, q2));
            const float e0 = expf(q0 - qm), e1q = expf(q1 - qm), e2q = expf(q2 - qm);
            const float qs = e0 + e1q + e2q;
            const float* u = &penu[(((size_t)t * B) + b) * 3];
            float* o = &out[(((size_t)t * B) + b) * 5];
            o[0] = tx / pe;
            o[1] = ty / pe;
            o[2] = (u[0] < e0  / qs) ? 1.f : 0.f;
            o[3] = (u[1] < e1q / qs) ? 1.f : 0.f;
            o[4] = (u[2] < e2q / qs) ? 1.f : 0.f;
        }
    }
}

// ---------------- latent chain ----------------
__global__ __launch_bounds__(256) void latent2(
    const float* __restrict__ hfT, const float* __restrict__ hbT,
    const float* __restrict__ Wmu, const float* __restrict__ bmu,
    const float* __restrict__ Wsig, const float* __restrict__ bsig,
    const float* __restrict__ zepsT, float* __restrict__ zT)
{
    const int lane = threadIdx.x & 63;
    const int wv   = __builtin_amdgcn_readfirstlane(threadIdx.x >> 6);
    const int b    = blockIdx.x * 64 + lane;
    const int n0   = blockIdx.y * 8 + wv * 2;

    float am[2] = {}, as2[2] = {};
    #pragma unroll 4
    for (int k0 = 0; k0 < 2 * EH; k0 += 4) {
        const float* hsrc = (k0 < EH) ? hfT : hbT;
        const int kk = k0 & (EH - 1);
        const float a0 = hsrc[(size_t)(kk + 0) * B + b];
        const float a1 = hsrc[(size_t)(kk + 1) * B + b];
        const float a2 = hsrc[(size_t)(kk + 2) * B + b];
        const float a3 = hsrc[(size_t)(kk + 3) * B + b];
        #pragma unroll
        for (int j = 0; j < 2; ++j) {
            const float4 wm = *(const float4*)&Wmu[((size_t)(n0 + j)) * (2 * EH) + k0];
            const float4 ws = *(const float4*)&Wsig[((size_t)(n0 + j)) * (2 * EH) + k0];
            float u = am[j], v = as2[j];
            u = fmaf(a0, wm.x, u); u = fmaf(a1, wm.y, u); u = fmaf(a2, wm.z, u); u = fmaf(a3, wm.w, u);
            v = fmaf(a0, ws.x, v); v = fmaf(a1, ws.y, v); v = fmaf(a2, ws.z, v); v = fmaf(a3, ws.w, v);
            am[j] = u; as2[j] = v;
        }
    }
    #pragma unroll
    for (int j = 0; j < 2; ++j) {
        const int n = n0 + j;
        const float mu = am[j] + bmu[n];
        const float sg = expf(0.5f * (as2[j] + bsig[n]));
        zT[(size_t)n * B + b] = fmaf(sg, zepsT[(size_t)n * B + b], mu);
    }
}

__global__ __launch_bounds__(256) void h02(
    const float* __restrict__ zT, const float* __restrict__ Wh0,
    const float* __restrict__ bh0, float* __restrict__ hT)
{
    const int lane = threadIdx.x & 63;
    const int wv   = __builtin_amdgcn_readfirstlane(threadIdx.x >> 6);
    const int b    = blockIdx.x * 64 + lane;
    const int n0   = blockIdx.y * 32 + wv * 8;

    float acc[8] = {};
    #pragma unroll 2
    for (int k0 = 0; k0 < ZS; k0 += 4) {
        const float a0 = zT[(size_t)(k0 + 0) * B + b];
        const float a1 = zT[(size_t)(k0 + 1) * B + b];
        const float a2 = zT[(size_t)(k0 + 2) * B + b];
        const float a3 = zT[(size_t)(k0 + 3) * B + b];
        #pragma unroll
        for (int r = 0; r < 8; ++r) {
            const float4 w = *(const float4*)&Wh0[((size_t)(n0 + r)) * ZS + k0];
            float v = acc[r];
            v = fmaf(a0, w.x, v); v = fmaf(a1, w.y, v);
            v = fmaf(a2, w.z, v); v = fmaf(a3, w.w, v);
            acc[r] = v;
        }
    }
    #pragma unroll
    for (int r = 0; r < 8; ++r)
        hT[(size_t)(n0 + r) * B + b] = tanhf(acc[r] + bh0[n0 + r]);
}

__global__ __launch_bounds__(256) void cz2(
    const float* __restrict__ zT, const float* __restrict__ Wih,
    const float* __restrict__ bias, float* __restrict__ CzT)
{
    const int lane = threadIdx.x & 63;
    const int wv   = __builtin_amdgcn_readfirstlane(threadIdx.x >> 6);
    const int b    = blockIdx.x * 64 + lane;
    const int r0   = blockIdx.y * 32 + wv * 8;

    float acc[8] = {};
    #pragma unroll 4
    for (int k = 0; k < ZS; ++k) {
        const float a = zT[(size_t)k * B + b];
        #pragma unroll
        for (int r = 0; r < 8; ++r)
            acc[r] = fmaf(a, Wih[(size_t)(r0 + r) * 133 + 5 + k], acc[r]);
    }
    #pragma unroll
    for (int r = 0; r < 8; ++r)
        CzT[(size_t)(r0 + r) * B + b] = acc[r] + bias[r0 + r];
}

extern "C" void kernel_launch(void* const* d_in, const int* in_sizes, int n_in,
                              void* d_out, int out_size, void* d_ws, size_t ws_size,
                              hipStream_t stream)
{
    (void)in_sizes; (void)n_in; (void)out_size; (void)ws_size;

    const float* s      = (const float*)d_in[0];
    const float* WihF   = (const float*)d_in[1];
    const float* WhhF   = (const float*)d_in[2];
    const float* bF     = (const float*)d_in[3];
    const float* WihB   = (const float*)d_in[4];
    const float* WhhB   = (const float*)d_in[5];
    const float* bB     = (const float*)d_in[6];
    const float* Wmu    = (const float*)d_in[7];
    const float* bmu    = (const float*)d_in[8];
    const float* Wsig   = (const float*)d_in[9];
    const float* bsig   = (const float*)d_in[10];
    const float* Wh0    = (const float*)d_in[11];
    const float* bh0    = (const float*)d_in[12];
    const float* decWih = (const float*)d_in[13];
    const float* decWhh = (const float*)d_in[14];
    const float* decB   = (const float*)d_in[15];
    const float* Wdec   = (const float*)d_in[16];
    const float* bdec   = (const float*)d_in[17];
    const float* zeps   = (const float*)d_in[18];
    const float* geps   = (const float*)d_in[19];
    const float* penu   = (const float*)d_in[20];

    float* out = (float*)d_out;
    float* p   = (float*)d_ws;

    float* hf0  = p; p += 131072;   // zeroed
    float* hb0  = p; p += 131072;   // zeroed
    float* cf   = p; p += 131072;   // zeroed
    float* cb   = p; p += 131072;   // zeroed
    float* cdT  = p; p += 262144;   // zeroed
    float* hf1  = p; p += 131072;
    float* hb1  = p; p += 131072;
    float* hA   = p; p += 262144;
    float* hB   = p; p += 262144;
    float* zT   = p; p += 65536;
    float* CzT  = p; p += 1048576;
    float* zepsT= p; p += 65536;
    float* WdecT= p; p += 65536;
    float* sT   = p; p += 327680;   // [128][5][512]

    hipMemsetAsync((void*)hf0, 0, (size_t)(4 * 131072 + 262144) * sizeof(float), stream);

    transpose_pad<<<dim3(256, 1, 1), 256, 0, stream>>>(zeps, zepsT, B, ZS, B, 0, 0);
    transpose_pad<<<dim3(256, 1, 1), 256, 0, stream>>>(Wdec, WdecT, 123, DH, 128, 0, 0);
    transpose_pad<<<dim3(10, 1, SEQL), 256, 0, stream>>>(s, sT, B, PT, B, (long)B * PT, (long)B * PT);

    for (int t = 0; t < SEQL; ++t) {
        const float* hfin = (t & 1) ? hf1 : hf0;  float* hfout = (t & 1) ? hf0 : hf1;
        const float* hbin = (t & 1) ? hb1 : hb0;  float* hbout = (t & 1) ? hb0 : hb1;
        enc_step5<<<dim3(512), 512, 0, stream>>>(
            sT, WihF, WhhF, bF, WihB, WhhB, bB,
            hfin, hfout, cf, hbin, hbout, cb, t);
    }
    // t=127 (odd) wrote hf0/hb0
    latent2<<<dim3(8, 16), 256, 0, stream>>>(hf0, hb0, Wmu, bmu, Wsig, bsig, zepsT, zT);
    h02<<<dim3(8, 16), 256, 0, stream>>>(zT, Wh0, bh0, hA);
    cz2<<<dim3(8, 64), 256, 0, stream>>>(zT, decWih, decB, CzT);

    for (int t = 0; t < NMAXT; ++t) {
        const float* hin = (t & 1) ? hB : hA;
        float* hout      = (t & 1) ? hA : hB;
        dec_step5<<<dim3(512), 512, 0, stream>>>(
            hin, hout, cdT, CzT, decWhh, decWih,
            t ? (out + (size_t)(t - 1) * B * 5) : out, t);
        ysamp6<<<dim3(128), 512, 0, stream>>>(hout, WdecT, bdec, geps, penu, out, t);
    }
}